// Round 1
// baseline (1121.527 us; speedup 1.0000x reference)
//
#include <hip/hip_runtime.h>
#include <hip/hip_bf16.h>

#define NN 10000
#define EE 160000
#define FF 128
#define UU 128
#define HH 8
#define BN_EPS 1e-3f

// ---------------- CSR construction ----------------
__global__ void k_hist(const int* __restrict__ eidx, int* __restrict__ cnt, int E) {
    int e = blockIdx.x * 256 + threadIdx.x;
    if (e < E) atomicAdd(&cnt[eidx[2 * e]], 1);   // dst = eidx[e][0]
}

__global__ void k_scan(const int* __restrict__ cnt, int* __restrict__ off,
                       int* __restrict__ cursor, int N) {
    __shared__ int s[1024];
    int t = threadIdx.x;
    int run = 0;
    if (t == 0) off[0] = 0;
    for (int base = 0; base < N; base += 1024) {
        int x = (base + t < N) ? cnt[base + t] : 0;
        s[t] = x;
        __syncthreads();
        for (int o = 1; o < 1024; o <<= 1) {
            int v = (t >= o) ? s[t - o] : 0;
            __syncthreads();
            s[t] += v;
            __syncthreads();
        }
        if (base + t < N) {
            off[base + t + 1] = run + s[t];
            cursor[base + t] = run + s[t] - x;
        }
        run += s[1023];
        __syncthreads();
    }
}

__global__ void k_scatter(const int* __restrict__ eidx, int* __restrict__ cursor,
                          int* __restrict__ elist, int E) {
    int e = blockIdx.x * 256 + threadIdx.x;
    if (e < E) {
        int d = eidx[2 * e];
        int p = atomicAdd(&cursor[d], 1);
        elist[p] = e;
    }
}

// ---------------- z = einsum('nf,hfu->hnu') + b_att, stored (N,H,U) ----------------
__global__ void k_z(const float* __restrict__ node, const float* __restrict__ Watt,
                    const float* __restrict__ batt, float* __restrict__ z, int N) {
    __shared__ float ash[32][128];
    int n0 = blockIdx.x * 32;
    int t = threadIdx.x;              // 256
    for (int q = t; q < 32 * 128; q += 256) {
        int m = q >> 7, c = q & 127;
        int n = n0 + m;
        ash[m][c] = (n < N) ? node[(size_t)n * 128 + c] : 0.f;
    }
    __syncthreads();
    int u = t & 127, g = t >> 7;      // g in {0,1}; rows g*16..g*16+15
    for (int h = 0; h < HH; ++h) {
        float acc[16];
        float b = batt[h * 128 + u];
#pragma unroll
        for (int m = 0; m < 16; ++m) acc[m] = b;
        const float* W = Watt + (size_t)h * 128 * 128 + u;
        for (int f = 0; f < 128; f += 4) {
            float w0 = W[(f + 0) * 128], w1 = W[(f + 1) * 128];
            float w2 = W[(f + 2) * 128], w3 = W[(f + 3) * 128];
#pragma unroll
            for (int m = 0; m < 16; ++m) {
                const float4 a = *reinterpret_cast<const float4*>(&ash[g * 16 + m][f]);
                acc[m] = fmaf(a.x, w0, acc[m]);
                acc[m] = fmaf(a.y, w1, acc[m]);
                acc[m] = fmaf(a.z, w2, acc[m]);
                acc[m] = fmaf(a.w, w3, acc[m]);
            }
        }
#pragma unroll
        for (int m = 0; m < 16; ++m) {
            int n = n0 + g * 16 + m;
            if (n < N) z[(size_t)n * 1024 + h * 128 + u] = acc[m];
        }
    }
}

// ---------------- s_src[n,h], s_dst[n,h] ----------------
__global__ void k_snodes(const float* __restrict__ z, const float* __restrict__ aatt,
                         float* __restrict__ s_src, float* __restrict__ s_dst, int N) {
    int n = blockIdx.x;
    int t = threadIdx.x;              // 128
    __shared__ float lds[4];
    for (int h = 0; h < HH; ++h) {
        float zv = z[(size_t)n * 1024 + h * 128 + t];
        float vs = zv * aatt[h * 384 + t];
        float vd = zv * aatt[h * 384 + 128 + t];
        for (int o = 32; o > 0; o >>= 1) {
            vs += __shfl_down(vs, o, 64);
            vd += __shfl_down(vd, o, 64);
        }
        int lane = t & 63, w = t >> 6;
        if (lane == 0) { lds[w * 2] = vs; lds[w * 2 + 1] = vd; }
        __syncthreads();
        if (t == 0) s_src[n * 8 + h] = lds[0] + lds[2];
        if (t == 1) s_dst[n * 8 + h] = lds[1] + lds[3];
        __syncthreads();
    }
}

// ---------------- edge MLP: relu(concat @ W_edge + b), partial BN stats ----------------
__global__ void k_edge_mlp(const float* __restrict__ node, const float* __restrict__ eattr,
                           const int* __restrict__ eidx, const float* __restrict__ We,
                           const float* __restrict__ be, float* __restrict__ ebuf,
                           float* __restrict__ part) {
    __shared__ float ash[32][384];
    __shared__ int sd[64];
    int e0 = blockIdx.x * 32;
    int t = threadIdx.x;              // 256
    if (t < 64) sd[t] = eidx[e0 * 2 + t];   // [e][0]=dst, [e][1]=src
    __syncthreads();
    for (int q = t; q < 32 * 384; q += 256) {
        int m = q / 384, c = q % 384;
        int dst = sd[m * 2], src = sd[m * 2 + 1];
        float v;
        if (c < 128)       v = node[(size_t)src * 128 + c];
        else if (c < 256)  v = node[(size_t)dst * 128 + (c - 128)];
        else               v = eattr[(size_t)(e0 + m) * 128 + (c - 256)];
        ash[m][c] = v;
    }
    __syncthreads();
    int u = t & 127, g = t >> 7;
    float acc[16];
    float b = be[u];
#pragma unroll
    for (int m = 0; m < 16; ++m) acc[m] = b;
    const float* W = We + u;
    for (int f = 0; f < 384; f += 4) {
        float w0 = W[(f + 0) * 128], w1 = W[(f + 1) * 128];
        float w2 = W[(f + 2) * 128], w3 = W[(f + 3) * 128];
#pragma unroll
        for (int m = 0; m < 16; ++m) {
            const float4 a = *reinterpret_cast<const float4*>(&ash[g * 16 + m][f]);
            acc[m] = fmaf(a.x, w0, acc[m]);
            acc[m] = fmaf(a.y, w1, acc[m]);
            acc[m] = fmaf(a.z, w2, acc[m]);
            acc[m] = fmaf(a.w, w3, acc[m]);
        }
    }
    float ls = 0.f, lq = 0.f;
#pragma unroll
    for (int m = 0; m < 16; ++m) {
        float r = acc[m] > 0.f ? acc[m] : 0.f;
        ebuf[(size_t)(e0 + g * 16 + m) * 128 + u] = r;
        ls += r;
        lq += r * r;
    }
    __syncthreads();                     // all GEMM LDS reads done
    float* red = (float*)ash;
    red[t] = ls;
    red[256 + t] = lq;
    __syncthreads();
    if (g == 0) {
        part[(size_t)blockIdx.x * 256 + u] = red[u] + red[128 + u];
        part[(size_t)blockIdx.x * 256 + 128 + u] = red[256 + u] + red[256 + 128 + u];
    }
}

// ---------------- BN finalize: scale/shift per column ----------------
__global__ void k_bn_fin(const float* __restrict__ part, int nblk, float invcnt,
                         const float* __restrict__ g, const float* __restrict__ b,
                         float* __restrict__ scale, float* __restrict__ shift) {
    int u = blockIdx.x;               // 128 blocks
    int t = threadIdx.x;              // 256
    float s = 0.f, q = 0.f;
    for (int i = t; i < nblk; i += 256) {
        s += part[(size_t)i * 256 + u];
        q += part[(size_t)i * 256 + 128 + u];
    }
    __shared__ float ls[4], lq[4];
    for (int o = 32; o > 0; o >>= 1) {
        s += __shfl_down(s, o, 64);
        q += __shfl_down(q, o, 64);
    }
    int lane = t & 63, w = t >> 6;
    if (lane == 0) { ls[w] = s; lq[w] = q; }
    __syncthreads();
    if (t == 0) {
        float S = ls[0] + ls[1] + ls[2] + ls[3];
        float Q = lq[0] + lq[1] + lq[2] + lq[3];
        float mean = S * invcnt;
        float var = Q * invcnt - mean * mean;
        float inv = rsqrtf(var + BN_EPS);
        float sc = g[u] * inv;
        scale[u] = sc;
        shift[u] = b[u] - mean * sc;
    }
}

// ---------------- edge finalize: BN apply, write out, s_edge ----------------
__global__ void k_edge_final(const float* __restrict__ ebuf, const float* __restrict__ scale,
                             const float* __restrict__ shift, const float* __restrict__ aatt,
                             float* __restrict__ eout, float* __restrict__ s_edge) {
    int e = blockIdx.x;
    int t = threadIdx.x;              // 128
    float x = ebuf[(size_t)e * 128 + t] * scale[t] + shift[t];
    eout[(size_t)e * 128 + t] = x;
    float v[8];
#pragma unroll
    for (int h = 0; h < 8; ++h) v[h] = x * aatt[h * 384 + 256 + t];
    for (int o = 32; o > 0; o >>= 1) {
#pragma unroll
        for (int h = 0; h < 8; ++h) v[h] += __shfl_down(v[h], o, 64);
    }
    __shared__ float lds[16];
    int lane = t & 63, w = t >> 6;
    if (lane == 0) {
#pragma unroll
        for (int h = 0; h < 8; ++h) lds[w * 8 + h] = v[h];
    }
    __syncthreads();
    if (t < 8) s_edge[e * 8 + t] = lds[t] + lds[8 + t];
}

// ---------------- attention softmax + aggregation (per dst node, all heads) ----------------
__global__ void k_agg(const float* __restrict__ z, const float* __restrict__ s_src,
                      const float* __restrict__ s_dst, const float* __restrict__ s_edge,
                      const int* __restrict__ off, const int* __restrict__ elist,
                      const int* __restrict__ eidx, float* __restrict__ att) {
    int n = blockIdx.x;
    int t = threadIdx.x;              // 128
    int beg = off[n], end = off[n + 1];
    int deg = end - beg;
    if (deg == 0) { att[(size_t)n * 128 + t] = 0.f; return; }

    float sdh[8];
#pragma unroll
    for (int h = 0; h < 8; ++h) sdh[h] = s_dst[n * 8 + h];

    __shared__ float lred[16];
    __shared__ float wbuf[128][8];
    __shared__ int snbuf[128];

    float mx[8], den[8];
#pragma unroll
    for (int h = 0; h < 8; ++h) { mx[h] = -1e30f; den[h] = 0.f; }

    int lane = t & 63, w = t >> 6;

    // pass 1: running max / denominator (online across chunks of 128)
    for (int c0 = 0; c0 < deg; c0 += 128) {
        int cn = min(128, deg - c0);
        bool act = t < cn;
        int e = 0, sn = 0;
        if (act) { e = elist[beg + c0 + t]; sn = eidx[2 * e + 1]; }
        float lg[8];
#pragma unroll
        for (int h = 0; h < 8; ++h) {
            float x = act ? (s_src[sn * 8 + h] + sdh[h] + s_edge[e * 8 + h]) : -1e30f;
            lg[h] = x >= 0.f ? x : 0.2f * x;
        }
        float cm[8];
#pragma unroll
        for (int h = 0; h < 8; ++h) cm[h] = lg[h];
        for (int o = 32; o > 0; o >>= 1) {
#pragma unroll
            for (int h = 0; h < 8; ++h) cm[h] = fmaxf(cm[h], __shfl_down(cm[h], o, 64));
        }
        if (lane == 0) {
#pragma unroll
            for (int h = 0; h < 8; ++h) lred[w * 8 + h] = cm[h];
        }
        __syncthreads();
#pragma unroll
        for (int h = 0; h < 8; ++h) cm[h] = fmaxf(lred[h], lred[8 + h]);
        __syncthreads();
        float cs[8];
#pragma unroll
        for (int h = 0; h < 8; ++h) cs[h] = act ? __expf(lg[h] - cm[h]) : 0.f;
        for (int o = 32; o > 0; o >>= 1) {
#pragma unroll
            for (int h = 0; h < 8; ++h) cs[h] += __shfl_down(cs[h], o, 64);
        }
        if (lane == 0) {
#pragma unroll
            for (int h = 0; h < 8; ++h) lred[w * 8 + h] = cs[h];
        }
        __syncthreads();
#pragma unroll
        for (int h = 0; h < 8; ++h) {
            float csum = lred[h] + lred[8 + h];
            float nm = fmaxf(mx[h], cm[h]);
            den[h] = den[h] * __expf(mx[h] - nm) + csum * __expf(cm[h] - nm);
            mx[h] = nm;
        }
        __syncthreads();
    }
    float inv[8];
#pragma unroll
    for (int h = 0; h < 8; ++h) inv[h] = 1.f / den[h];

    // pass 2: weights into LDS, then accumulate sum over heads of alpha*z[src]
    float acc = 0.f;
    for (int c0 = 0; c0 < deg; c0 += 128) {
        int cn = min(128, deg - c0);
        if (t < cn) {
            int e = elist[beg + c0 + t];
            int sn = eidx[2 * e + 1];
            snbuf[t] = sn;
#pragma unroll
            for (int h = 0; h < 8; ++h) {
                float x = s_src[sn * 8 + h] + sdh[h] + s_edge[e * 8 + h];
                x = x >= 0.f ? x : 0.2f * x;
                wbuf[t][h] = __expf(x - mx[h]) * inv[h];
            }
        }
        __syncthreads();
        for (int i = 0; i < cn; ++i) {
            int sn = snbuf[i];
            const float* zr = z + (size_t)sn * 1024 + t;
#pragma unroll
            for (int h = 0; h < 8; ++h)
                acc = fmaf(wbuf[i][h], zr[h * 128], acc);
        }
        __syncthreads();
    }
    att[(size_t)n * 128 + t] = fmaxf(acc * 0.125f, 0.f);
}

// ---------------- node MLP: relu(node @ W_node + b), partial BN stats ----------------
__global__ void k_node_mlp(const float* __restrict__ node, const float* __restrict__ Wn,
                           const float* __restrict__ bn, float* __restrict__ nupd,
                           float* __restrict__ part, int N) {
    __shared__ float ash[32][128];
    int n0 = blockIdx.x * 32;
    int t = threadIdx.x;              // 256
    for (int q = t; q < 32 * 128; q += 256) {
        int m = q >> 7, c = q & 127;
        int n = n0 + m;
        ash[m][c] = (n < N) ? node[(size_t)n * 128 + c] : 0.f;
    }
    __syncthreads();
    int u = t & 127, g = t >> 7;
    float acc[16];
    float b = bn[u];
#pragma unroll
    for (int m = 0; m < 16; ++m) acc[m] = b;
    const float* W = Wn + u;
    for (int f = 0; f < 128; f += 4) {
        float w0 = W[(f + 0) * 128], w1 = W[(f + 1) * 128];
        float w2 = W[(f + 2) * 128], w3 = W[(f + 3) * 128];
#pragma unroll
        for (int m = 0; m < 16; ++m) {
            const float4 a = *reinterpret_cast<const float4*>(&ash[g * 16 + m][f]);
            acc[m] = fmaf(a.x, w0, acc[m]);
            acc[m] = fmaf(a.y, w1, acc[m]);
            acc[m] = fmaf(a.z, w2, acc[m]);
            acc[m] = fmaf(a.w, w3, acc[m]);
        }
    }
    float ls = 0.f, lq = 0.f;
#pragma unroll
    for (int m = 0; m < 16; ++m) {
        int n = n0 + g * 16 + m;
        float r = acc[m] > 0.f ? acc[m] : 0.f;
        if (n < N) {
            nupd[(size_t)n * 128 + u] = r;
            ls += r;
            lq += r * r;
        }
    }
    __syncthreads();
    float* red = (float*)ash;
    red[t] = ls;
    red[256 + t] = lq;
    __syncthreads();
    if (g == 0) {
        part[(size_t)blockIdx.x * 256 + u] = red[u] + red[128 + u];
        part[(size_t)blockIdx.x * 256 + 128 + u] = red[256 + u] + red[256 + 128 + u];
    }
}

// ---------------- GRU combine ----------------
__global__ void k_gru(const float* __restrict__ att, const float* __restrict__ nupd,
                      const float* __restrict__ scale, const float* __restrict__ shift,
                      const float* __restrict__ Wk, const float* __restrict__ Wr,
                      const float* __restrict__ gbias, float* __restrict__ outp) {
    __shared__ float ash[16][128];
    __shared__ float ush[16][128];
    __shared__ float zg[16][128];
    __shared__ float rg[16][128];
    int n0 = blockIdx.x * 16;
    int t = threadIdx.x;              // 128
    for (int m = 0; m < 16; ++m) {
        ash[m][t] = att[(size_t)(n0 + m) * 128 + t];
        ush[m][t] = nupd[(size_t)(n0 + m) * 128 + t] * scale[t] + shift[t];
    }
    __syncthreads();
    for (int c = 0; c < 3; ++c) {
        float ax[16], ar[16];
        float bx = gbias[c * 128 + t];
        float br = gbias[384 + c * 128 + t];
#pragma unroll
        for (int m = 0; m < 16; ++m) { ax[m] = bx; ar[m] = br; }
        const float* wkp = Wk + c * 128 + t;
        const float* wrp = Wr + c * 128 + t;
        for (int uu = 0; uu < 128; uu += 4) {
            float wk0 = wkp[(uu + 0) * 384], wk1 = wkp[(uu + 1) * 384];
            float wk2 = wkp[(uu + 2) * 384], wk3 = wkp[(uu + 3) * 384];
            float wr0 = wrp[(uu + 0) * 384], wr1 = wrp[(uu + 1) * 384];
            float wr2 = wrp[(uu + 2) * 384], wr3 = wrp[(uu + 3) * 384];
#pragma unroll
            for (int m = 0; m < 16; ++m) {
                const float4 av = *reinterpret_cast<const float4*>(&ash[m][uu]);
                const float4 uv = *reinterpret_cast<const float4*>(&ush[m][uu]);
                ax[m] = fmaf(av.x, wk0, ax[m]); ax[m] = fmaf(av.y, wk1, ax[m]);
                ax[m] = fmaf(av.z, wk2, ax[m]); ax[m] = fmaf(av.w, wk3, ax[m]);
                ar[m] = fmaf(uv.x, wr0, ar[m]); ar[m] = fmaf(uv.y, wr1, ar[m]);
                ar[m] = fmaf(uv.z, wr2, ar[m]); ar[m] = fmaf(uv.w, wr3, ar[m]);
            }
        }
        if (c == 0) {
#pragma unroll
            for (int m = 0; m < 16; ++m)
                zg[m][t] = 1.f / (1.f + __expf(-(ax[m] + ar[m])));
        } else if (c == 1) {
#pragma unroll
            for (int m = 0; m < 16; ++m)
                rg[m][t] = 1.f / (1.f + __expf(-(ax[m] + ar[m])));
        } else {
#pragma unroll
            for (int m = 0; m < 16; ++m) {
                float hh = tanhf(ax[m] + rg[m][t] * ar[m]);
                float zv = zg[m][t];
                outp[(size_t)(n0 + m) * 128 + t] = zv * ush[m][t] + (1.f - zv) * hh;
            }
        }
    }
}

// ---------------- launch ----------------
extern "C" void kernel_launch(void* const* d_in, const int* in_sizes, int n_in,
                              void* d_out, int out_size, void* d_ws, size_t ws_size,
                              hipStream_t stream) {
    const float* node    = (const float*)d_in[0];
    const float* eattr   = (const float*)d_in[1];
    const int*   eidx    = (const int*)d_in[2];
    const float* We      = (const float*)d_in[3];
    const float* be      = (const float*)d_in[4];
    const float* gamma_e = (const float*)d_in[5];
    const float* beta_e  = (const float*)d_in[6];
    const float* Wn      = (const float*)d_in[7];
    const float* bnb     = (const float*)d_in[8];
    const float* gamma_n = (const float*)d_in[9];
    const float* beta_n  = (const float*)d_in[10];
    const float* Watt    = (const float*)d_in[11];
    const float* batt    = (const float*)d_in[12];
    const float* aatt    = (const float*)d_in[13];
    const float* Wk      = (const float*)d_in[14];
    const float* Wr      = (const float*)d_in[15];
    const float* gbias   = (const float*)d_in[16];

    float* out_node = (float*)d_out;
    float* out_edge = out_node + (size_t)NN * UU;

    char* wp = (char*)d_ws;
    auto alloc = [&](size_t bytes) {
        void* p = (void*)wp;
        wp += (bytes + 255) / 256 * 256;
        return p;
    };
    float* z       = (float*)alloc((size_t)NN * 1024 * 4);
    float* ebuf    = (float*)alloc((size_t)EE * 128 * 4);
    float* s_src   = (float*)alloc((size_t)NN * 8 * 4);
    float* s_dst   = (float*)alloc((size_t)NN * 8 * 4);
    float* s_edge  = (float*)alloc((size_t)EE * 8 * 4);
    float* part_e  = (float*)alloc((size_t)5000 * 256 * 4);
    float* part_n  = (float*)alloc((size_t)313 * 256 * 4);
    float* scale_e = (float*)alloc(512);
    float* shift_e = (float*)alloc(512);
    float* scale_n = (float*)alloc(512);
    float* shift_n = (float*)alloc(512);
    float* attend  = (float*)alloc((size_t)NN * 128 * 4);
    float* nupd    = (float*)alloc((size_t)NN * 128 * 4);
    int*   cnt     = (int*)alloc((size_t)NN * 4);
    int*   offs    = (int*)alloc((size_t)(NN + 1) * 4);
    int*   cursor  = (int*)alloc((size_t)NN * 4);
    int*   elist   = (int*)alloc((size_t)EE * 4);

    hipMemsetAsync(cnt, 0, (size_t)NN * 4, stream);
    k_hist<<<(EE + 255) / 256, 256, 0, stream>>>(eidx, cnt, EE);
    k_scan<<<1, 1024, 0, stream>>>(cnt, offs, cursor, NN);
    k_scatter<<<(EE + 255) / 256, 256, 0, stream>>>(eidx, cursor, elist, EE);

    k_z<<<(NN + 31) / 32, 256, 0, stream>>>(node, Watt, batt, z, NN);
    k_snodes<<<NN, 128, 0, stream>>>(z, aatt, s_src, s_dst, NN);

    k_edge_mlp<<<EE / 32, 256, 0, stream>>>(node, eattr, eidx, We, be, ebuf, part_e);
    k_bn_fin<<<128, 256, 0, stream>>>(part_e, EE / 32, 1.f / (float)EE,
                                      gamma_e, beta_e, scale_e, shift_e);
    k_edge_final<<<EE, 128, 0, stream>>>(ebuf, scale_e, shift_e, aatt, out_edge, s_edge);

    k_agg<<<NN, 128, 0, stream>>>(z, s_src, s_dst, s_edge, offs, elist, eidx, attend);

    k_node_mlp<<<(NN + 31) / 32, 256, 0, stream>>>(node, Wn, bnb, nupd, part_n, NN);
    k_bn_fin<<<128, 256, 0, stream>>>(part_n, (NN + 31) / 32, 1.f / (float)NN,
                                      gamma_n, beta_n, scale_n, shift_n);
    k_gru<<<NN / 16, 128, 0, stream>>>(attend, nupd, scale_n, shift_n, Wk, Wr, gbias, out_node);
}

// Round 2
// 755.214 us; speedup vs baseline: 1.4850x; 1.4850x over previous
//
#include <hip/hip_runtime.h>
#include <hip/hip_bf16.h>

#define NN 10000
#define EE 160000
#define FF 128
#define UU 128
#define HH 8
#define BN_EPS 1e-3f

typedef __attribute__((ext_vector_type(8))) short bf16x8;
typedef __attribute__((ext_vector_type(4))) float f32x4;

static __device__ __forceinline__ unsigned short f2bf(float f) {
    unsigned u = __float_as_uint(f);
    u += 0x7fffu + ((u >> 16) & 1u);
    return (unsigned short)(u >> 16);
}

// ---------------- f32 -> bf16 bulk convert (count divisible by 4) ----------------
__global__ void k_f2bf(const float* __restrict__ in, unsigned short* __restrict__ out, long n4) {
    long i = (long)blockIdx.x * 256 + threadIdx.x;
    long stride = (long)gridDim.x * 256;
    for (; i < n4; i += stride) {
        float4 v = reinterpret_cast<const float4*>(in)[i];
        ushort4 o;
        o.x = f2bf(v.x); o.y = f2bf(v.y); o.z = f2bf(v.z); o.w = f2bf(v.w);
        reinterpret_cast<ushort4*>(out)[i] = o;
    }
}

// ---------------- W_edge [384][128] f32 -> W^T [128][384] bf16 ----------------
__global__ void k_wt(const float* __restrict__ W, unsigned short* __restrict__ Wt) {
    int i = blockIdx.x * 256 + threadIdx.x;   // i over 384*128
    if (i < 384 * 128) {
        int k = i >> 7, u = i & 127;
        Wt[u * 384 + k] = f2bf(W[i]);
    }
}

// ---------------- CSR construction ----------------
__global__ void k_hist(const int* __restrict__ eidx, int* __restrict__ cnt, int E) {
    int e = blockIdx.x * 256 + threadIdx.x;
    if (e < E) atomicAdd(&cnt[eidx[2 * e]], 1);   // dst = eidx[e][0]
}

__global__ void k_scan(const int* __restrict__ cnt, int* __restrict__ off,
                       int* __restrict__ cursor, int N) {
    __shared__ int s[1024];
    int t = threadIdx.x;
    int run = 0;
    if (t == 0) off[0] = 0;
    for (int base = 0; base < N; base += 1024) {
        int x = (base + t < N) ? cnt[base + t] : 0;
        s[t] = x;
        __syncthreads();
        for (int o = 1; o < 1024; o <<= 1) {
            int v = (t >= o) ? s[t - o] : 0;
            __syncthreads();
            s[t] += v;
            __syncthreads();
        }
        if (base + t < N) {
            off[base + t + 1] = run + s[t];
            cursor[base + t] = run + s[t] - x;
        }
        run += s[1023];
        __syncthreads();
    }
}

__global__ void k_scatter(const int* __restrict__ eidx, int* __restrict__ cursor,
                          int* __restrict__ elist, int E) {
    int e = blockIdx.x * 256 + threadIdx.x;
    if (e < E) {
        int d = eidx[2 * e];
        int p = atomicAdd(&cursor[d], 1);
        elist[p] = e;
    }
}

// ---------------- z = einsum('nf,hfu->hnu') + b_att, stored (N,H,U) ----------------
__global__ void k_z(const float* __restrict__ node, const float* __restrict__ Watt,
                    const float* __restrict__ batt, float* __restrict__ z, int N) {
    __shared__ float ash[32][128];
    int n0 = blockIdx.x * 32;
    int t = threadIdx.x;              // 256
    for (int q = t; q < 32 * 128; q += 256) {
        int m = q >> 7, c = q & 127;
        int n = n0 + m;
        ash[m][c] = (n < N) ? node[(size_t)n * 128 + c] : 0.f;
    }
    __syncthreads();
    int u = t & 127, g = t >> 7;      // g in {0,1}; rows g*16..g*16+15
    for (int h = 0; h < HH; ++h) {
        float acc[16];
        float b = batt[h * 128 + u];
#pragma unroll
        for (int m = 0; m < 16; ++m) acc[m] = b;
        const float* W = Watt + (size_t)h * 128 * 128 + u;
        for (int f = 0; f < 128; f += 4) {
            float w0 = W[(f + 0) * 128], w1 = W[(f + 1) * 128];
            float w2 = W[(f + 2) * 128], w3 = W[(f + 3) * 128];
#pragma unroll
            for (int m = 0; m < 16; ++m) {
                const float4 a = *reinterpret_cast<const float4*>(&ash[g * 16 + m][f]);
                acc[m] = fmaf(a.x, w0, acc[m]);
                acc[m] = fmaf(a.y, w1, acc[m]);
                acc[m] = fmaf(a.z, w2, acc[m]);
                acc[m] = fmaf(a.w, w3, acc[m]);
            }
        }
#pragma unroll
        for (int m = 0; m < 16; ++m) {
            int n = n0 + g * 16 + m;
            if (n < N) z[(size_t)n * 1024 + h * 128 + u] = acc[m];
        }
    }
}

// ---------------- s_src[n,h], s_dst[n,h] ----------------
__global__ void k_snodes(const float* __restrict__ z, const float* __restrict__ aatt,
                         float* __restrict__ s_src, float* __restrict__ s_dst, int N) {
    int n = blockIdx.x;
    int t = threadIdx.x;              // 128
    __shared__ float lds[4];
    for (int h = 0; h < HH; ++h) {
        float zv = z[(size_t)n * 1024 + h * 128 + t];
        float vs = zv * aatt[h * 384 + t];
        float vd = zv * aatt[h * 384 + 128 + t];
        for (int o = 32; o > 0; o >>= 1) {
            vs += __shfl_down(vs, o, 64);
            vd += __shfl_down(vd, o, 64);
        }
        int lane = t & 63, w = t >> 6;
        if (lane == 0) { lds[w * 2] = vs; lds[w * 2 + 1] = vd; }
        __syncthreads();
        if (t == 0) s_src[n * 8 + h] = lds[0] + lds[2];
        if (t == 1) s_dst[n * 8 + h] = lds[1] + lds[3];
        __syncthreads();
    }
}

// ---------------- edge MLP via MFMA bf16: relu(concat @ W_edge + b), BN partials ----------------
// 64 edges x 128 outputs per block, 4 waves (2x2), mfma_f32_16x16x32_bf16.
__global__ void __launch_bounds__(256) k_edge_mlp_mfma(
        const unsigned short* __restrict__ node_bf, const unsigned short* __restrict__ eattr_bf,
        const int* __restrict__ eidx, const unsigned short* __restrict__ Wt,
        const float* __restrict__ be, float* __restrict__ ebuf, float* __restrict__ part) {
    __shared__ unsigned short ash[64][392];     // 384 + 8 pad -> 784B row stride
    __shared__ int sd[128];
    __shared__ float sbuf[4][64], qbuf[4][64];
    int e0 = blockIdx.x * 64;
    int t = threadIdx.x;
    if (t < 128) sd[t] = eidx[e0 * 2 + t];      // [e][0]=dst, [e][1]=src
    __syncthreads();
    // gather 64 rows x 48 16B-chunks
    for (int q = t; q < 64 * 48; q += 256) {
        int r = q / 48, c = q - r * 48;
        const unsigned short* sp;
        if (c < 16)      sp = node_bf + (size_t)sd[r * 2 + 1] * 128 + c * 8;
        else if (c < 32) sp = node_bf + (size_t)sd[r * 2] * 128 + (c - 16) * 8;
        else             sp = eattr_bf + (size_t)(e0 + r) * 128 + (c - 32) * 8;
        *reinterpret_cast<uint4*>(&ash[r][c * 8]) = *reinterpret_cast<const uint4*>(sp);
    }
    __syncthreads();

    int wid = t >> 6, lane = t & 63;
    int wm = wid >> 1, wn = wid & 1;
    int lr = lane & 15, lg = lane >> 4;

    f32x4 acc[2][4];
#pragma unroll
    for (int m = 0; m < 2; ++m)
#pragma unroll
        for (int n = 0; n < 4; ++n) acc[m][n] = (f32x4){0.f, 0.f, 0.f, 0.f};

#pragma unroll
    for (int ks = 0; ks < 12; ++ks) {
        int kb = ks * 32 + lg * 8;
        bf16x8 a0 = *reinterpret_cast<const bf16x8*>(&ash[wm * 32 + lr][kb]);
        bf16x8 a1 = *reinterpret_cast<const bf16x8*>(&ash[wm * 32 + 16 + lr][kb]);
        bf16x8 b[4];
#pragma unroll
        for (int n = 0; n < 4; ++n)
            b[n] = *reinterpret_cast<const bf16x8*>(Wt + (size_t)(wn * 64 + n * 16 + lr) * 384 + kb);
#pragma unroll
        for (int n = 0; n < 4; ++n) {
            acc[0][n] = __builtin_amdgcn_mfma_f32_16x16x32_bf16(a0, b[n], acc[0][n], 0, 0, 0);
            acc[1][n] = __builtin_amdgcn_mfma_f32_16x16x32_bf16(a1, b[n], acc[1][n], 0, 0, 0);
        }
    }

    // epilogue: bias + relu + store f32 + per-column BN partials
    float s[4] = {0.f, 0.f, 0.f, 0.f}, q[4] = {0.f, 0.f, 0.f, 0.f};
#pragma unroll
    for (int n = 0; n < 4; ++n) {
        int col = wn * 64 + n * 16 + lr;
        float bias = be[col];
#pragma unroll
        for (int m = 0; m < 2; ++m) {
            int rowb = wm * 32 + m * 16 + lg * 4;
#pragma unroll
            for (int r = 0; r < 4; ++r) {
                float v = acc[m][n][r] + bias;
                v = v > 0.f ? v : 0.f;
                ebuf[(size_t)(e0 + rowb + r) * 128 + col] = v;
                s[n] += v;
                q[n] += v * v;
            }
        }
    }
#pragma unroll
    for (int n = 0; n < 4; ++n) {
        s[n] += __shfl_xor(s[n], 16, 64);
        s[n] += __shfl_xor(s[n], 32, 64);
        q[n] += __shfl_xor(q[n], 16, 64);
        q[n] += __shfl_xor(q[n], 32, 64);
    }
    if (lane < 16) {
#pragma unroll
        for (int n = 0; n < 4; ++n) {
            sbuf[wid][n * 16 + lane] = s[n];
            qbuf[wid][n * 16 + lane] = q[n];
        }
    }
    __syncthreads();
    if (t < 128) {
        int half = t >> 6, c = t & 63;
        part[(size_t)blockIdx.x * 256 + t] = sbuf[half][c] + sbuf[2 + half][c];
        part[(size_t)blockIdx.x * 256 + 128 + t] = qbuf[half][c] + qbuf[2 + half][c];
    }
}

// ---------------- BN finalize: scale/shift per column ----------------
__global__ void k_bn_fin(const float* __restrict__ part, int nblk, float invcnt,
                         const float* __restrict__ g, const float* __restrict__ b,
                         float* __restrict__ scale, float* __restrict__ shift) {
    int u = blockIdx.x;               // 128 blocks
    int t = threadIdx.x;              // 256
    float s = 0.f, q = 0.f;
    for (int i = t; i < nblk; i += 256) {
        s += part[(size_t)i * 256 + u];
        q += part[(size_t)i * 256 + 128 + u];
    }
    __shared__ float ls[4], lq[4];
    for (int o = 32; o > 0; o >>= 1) {
        s += __shfl_down(s, o, 64);
        q += __shfl_down(q, o, 64);
    }
    int lane = t & 63, w = t >> 6;
    if (lane == 0) { ls[w] = s; lq[w] = q; }
    __syncthreads();
    if (t == 0) {
        float S = ls[0] + ls[1] + ls[2] + ls[3];
        float Q = lq[0] + lq[1] + lq[2] + lq[3];
        float mean = S * invcnt;
        float var = Q * invcnt - mean * mean;
        float inv = rsqrtf(var + BN_EPS);
        float sc = g[u] * inv;
        scale[u] = sc;
        shift[u] = b[u] - mean * sc;
    }
}

// ---------------- edge finalize: BN apply, write out, s_edge ----------------
__global__ void k_edge_final(const float* __restrict__ ebuf, const float* __restrict__ scale,
                             const float* __restrict__ shift, const float* __restrict__ aatt,
                             float* __restrict__ eout, float* __restrict__ s_edge) {
    int e = blockIdx.x;
    int t = threadIdx.x;              // 128
    float x = ebuf[(size_t)e * 128 + t] * scale[t] + shift[t];
    eout[(size_t)e * 128 + t] = x;
    float v[8];
#pragma unroll
    for (int h = 0; h < 8; ++h) v[h] = x * aatt[h * 384 + 256 + t];
    for (int o = 32; o > 0; o >>= 1) {
#pragma unroll
        for (int h = 0; h < 8; ++h) v[h] += __shfl_down(v[h], o, 64);
    }
    __shared__ float lds[16];
    int lane = t & 63, w = t >> 6;
    if (lane == 0) {
#pragma unroll
        for (int h = 0; h < 8; ++h) lds[w * 8 + h] = v[h];
    }
    __syncthreads();
    if (t < 8) s_edge[e * 8 + t] = lds[t] + lds[8 + t];
}

// ---------------- attention softmax + aggregation (per dst node, all heads) ----------------
__global__ void k_agg(const float* __restrict__ z, const float* __restrict__ s_src,
                      const float* __restrict__ s_dst, const float* __restrict__ s_edge,
                      const int* __restrict__ off, const int* __restrict__ elist,
                      const int* __restrict__ eidx, float* __restrict__ att) {
    int n = blockIdx.x;
    int t = threadIdx.x;              // 128
    int beg = off[n], end = off[n + 1];
    int deg = end - beg;
    if (deg == 0) { att[(size_t)n * 128 + t] = 0.f; return; }

    float sdh[8];
#pragma unroll
    for (int h = 0; h < 8; ++h) sdh[h] = s_dst[n * 8 + h];

    __shared__ float lred[16];
    __shared__ float wbuf[128][8];
    __shared__ int snbuf[128];

    float mx[8], den[8];
#pragma unroll
    for (int h = 0; h < 8; ++h) { mx[h] = -1e30f; den[h] = 0.f; }

    int lane = t & 63, w = t >> 6;

    // pass 1: running max / denominator (online across chunks of 128)
    for (int c0 = 0; c0 < deg; c0 += 128) {
        int cn = min(128, deg - c0);
        bool act = t < cn;
        int e = 0, sn = 0;
        if (act) { e = elist[beg + c0 + t]; sn = eidx[2 * e + 1]; }
        float lg[8];
#pragma unroll
        for (int h = 0; h < 8; ++h) {
            float x = act ? (s_src[sn * 8 + h] + sdh[h] + s_edge[e * 8 + h]) : -1e30f;
            lg[h] = x >= 0.f ? x : 0.2f * x;
        }
        float cm[8];
#pragma unroll
        for (int h = 0; h < 8; ++h) cm[h] = lg[h];
        for (int o = 32; o > 0; o >>= 1) {
#pragma unroll
            for (int h = 0; h < 8; ++h) cm[h] = fmaxf(cm[h], __shfl_down(cm[h], o, 64));
        }
        if (lane == 0) {
#pragma unroll
            for (int h = 0; h < 8; ++h) lred[w * 8 + h] = cm[h];
        }
        __syncthreads();
#pragma unroll
        for (int h = 0; h < 8; ++h) cm[h] = fmaxf(lred[h], lred[8 + h]);
        __syncthreads();
        float cs[8];
#pragma unroll
        for (int h = 0; h < 8; ++h) cs[h] = act ? __expf(lg[h] - cm[h]) : 0.f;
        for (int o = 32; o > 0; o >>= 1) {
#pragma unroll
            for (int h = 0; h < 8; ++h) cs[h] += __shfl_down(cs[h], o, 64);
        }
        if (lane == 0) {
#pragma unroll
            for (int h = 0; h < 8; ++h) lred[w * 8 + h] = cs[h];
        }
        __syncthreads();
#pragma unroll
        for (int h = 0; h < 8; ++h) {
            float csum = lred[h] + lred[8 + h];
            float nm = fmaxf(mx[h], cm[h]);
            den[h] = den[h] * __expf(mx[h] - nm) + csum * __expf(cm[h] - nm);
            mx[h] = nm;
        }
        __syncthreads();
    }
    float inv[8];
#pragma unroll
    for (int h = 0; h < 8; ++h) inv[h] = 1.f / den[h];

    // pass 2: weights into LDS, then accumulate sum over heads of alpha*z[src]
    float acc = 0.f;
    for (int c0 = 0; c0 < deg; c0 += 128) {
        int cn = min(128, deg - c0);
        if (t < cn) {
            int e = elist[beg + c0 + t];
            int sn = eidx[2 * e + 1];
            snbuf[t] = sn;
#pragma unroll
            for (int h = 0; h < 8; ++h) {
                float x = s_src[sn * 8 + h] + sdh[h] + s_edge[e * 8 + h];
                x = x >= 0.f ? x : 0.2f * x;
                wbuf[t][h] = __expf(x - mx[h]) * inv[h];
            }
        }
        __syncthreads();
        for (int i = 0; i < cn; ++i) {
            int sn = snbuf[i];
            const float* zr = z + (size_t)sn * 1024 + t;
#pragma unroll
            for (int h = 0; h < 8; ++h)
                acc = fmaf(wbuf[i][h], zr[h * 128], acc);
        }
        __syncthreads();
    }
    att[(size_t)n * 128 + t] = fmaxf(acc * 0.125f, 0.f);
}

// ---------------- node MLP: relu(node @ W_node + b), partial BN stats ----------------
__global__ void k_node_mlp(const float* __restrict__ node, const float* __restrict__ Wn,
                           const float* __restrict__ bn, float* __restrict__ nupd,
                           float* __restrict__ part, int N) {
    __shared__ float ash[32][128];
    int n0 = blockIdx.x * 32;
    int t = threadIdx.x;              // 256
    for (int q = t; q < 32 * 128; q += 256) {
        int m = q >> 7, c = q & 127;
        int n = n0 + m;
        ash[m][c] = (n < N) ? node[(size_t)n * 128 + c] : 0.f;
    }
    __syncthreads();
    int u = t & 127, g = t >> 7;
    float acc[16];
    float b = bn[u];
#pragma unroll
    for (int m = 0; m < 16; ++m) acc[m] = b;
    const float* W = Wn + u;
    for (int f = 0; f < 128; f += 4) {
        float w0 = W[(f + 0) * 128], w1 = W[(f + 1) * 128];
        float w2 = W[(f + 2) * 128], w3 = W[(f + 3) * 128];
#pragma unroll
        for (int m = 0; m < 16; ++m) {
            const float4 a = *reinterpret_cast<const float4*>(&ash[g * 16 + m][f]);
            acc[m] = fmaf(a.x, w0, acc[m]);
            acc[m] = fmaf(a.y, w1, acc[m]);
            acc[m] = fmaf(a.z, w2, acc[m]);
            acc[m] = fmaf(a.w, w3, acc[m]);
        }
    }
    float ls = 0.f, lq = 0.f;
#pragma unroll
    for (int m = 0; m < 16; ++m) {
        int n = n0 + g * 16 + m;
        float r = acc[m] > 0.f ? acc[m] : 0.f;
        if (n < N) {
            nupd[(size_t)n * 128 + u] = r;
            ls += r;
            lq += r * r;
        }
    }
    __syncthreads();
    float* red = (float*)ash;
    red[t] = ls;
    red[256 + t] = lq;
    __syncthreads();
    if (g == 0) {
        part[(size_t)blockIdx.x * 256 + u] = red[u] + red[128 + u];
        part[(size_t)blockIdx.x * 256 + 128 + u] = red[256 + u] + red[256 + 128 + u];
    }
}

// ---------------- GRU combine ----------------
__global__ void k_gru(const float* __restrict__ att, const float* __restrict__ nupd,
                      const float* __restrict__ scale, const float* __restrict__ shift,
                      const float* __restrict__ Wk, const float* __restrict__ Wr,
                      const float* __restrict__ gbias, float* __restrict__ outp) {
    __shared__ float ash[16][128];
    __shared__ float ush[16][128];
    __shared__ float zg[16][128];
    __shared__ float rg[16][128];
    int n0 = blockIdx.x * 16;
    int t = threadIdx.x;              // 128
    for (int m = 0; m < 16; ++m) {
        ash[m][t] = att[(size_t)(n0 + m) * 128 + t];
        ush[m][t] = nupd[(size_t)(n0 + m) * 128 + t] * scale[t] + shift[t];
    }
    __syncthreads();
    for (int c = 0; c < 3; ++c) {
        float ax[16], ar[16];
        float bx = gbias[c * 128 + t];
        float br = gbias[384 + c * 128 + t];
#pragma unroll
        for (int m = 0; m < 16; ++m) { ax[m] = bx; ar[m] = br; }
        const float* wkp = Wk + c * 128 + t;
        const float* wrp = Wr + c * 128 + t;
        for (int uu = 0; uu < 128; uu += 4) {
            float wk0 = wkp[(uu + 0) * 384], wk1 = wkp[(uu + 1) * 384];
            float wk2 = wkp[(uu + 2) * 384], wk3 = wkp[(uu + 3) * 384];
            float wr0 = wrp[(uu + 0) * 384], wr1 = wrp[(uu + 1) * 384];
            float wr2 = wrp[(uu + 2) * 384], wr3 = wrp[(uu + 3) * 384];
#pragma unroll
            for (int m = 0; m < 16; ++m) {
                const float4 av = *reinterpret_cast<const float4*>(&ash[m][uu]);
                const float4 uv = *reinterpret_cast<const float4*>(&ush[m][uu]);
                ax[m] = fmaf(av.x, wk0, ax[m]); ax[m] = fmaf(av.y, wk1, ax[m]);
                ax[m] = fmaf(av.z, wk2, ax[m]); ax[m] = fmaf(av.w, wk3, ax[m]);
                ar[m] = fmaf(uv.x, wr0, ar[m]); ar[m] = fmaf(uv.y, wr1, ar[m]);
                ar[m] = fmaf(uv.z, wr2, ar[m]); ar[m] = fmaf(uv.w, wr3, ar[m]);
            }
        }
        if (c == 0) {
#pragma unroll
            for (int m = 0; m < 16; ++m)
                zg[m][t] = 1.f / (1.f + __expf(-(ax[m] + ar[m])));
        } else if (c == 1) {
#pragma unroll
            for (int m = 0; m < 16; ++m)
                rg[m][t] = 1.f / (1.f + __expf(-(ax[m] + ar[m])));
        } else {
#pragma unroll
            for (int m = 0; m < 16; ++m) {
                float hh = tanhf(ax[m] + rg[m][t] * ar[m]);
                float zv = zg[m][t];
                outp[(size_t)(n0 + m) * 128 + t] = zv * ush[m][t] + (1.f - zv) * hh;
            }
        }
    }
}

// ---------------- launch ----------------
extern "C" void kernel_launch(void* const* d_in, const int* in_sizes, int n_in,
                              void* d_out, int out_size, void* d_ws, size_t ws_size,
                              hipStream_t stream) {
    const float* node    = (const float*)d_in[0];
    const float* eattr   = (const float*)d_in[1];
    const int*   eidx    = (const int*)d_in[2];
    const float* We      = (const float*)d_in[3];
    const float* be      = (const float*)d_in[4];
    const float* gamma_e = (const float*)d_in[5];
    const float* beta_e  = (const float*)d_in[6];
    const float* Wn      = (const float*)d_in[7];
    const float* bnb     = (const float*)d_in[8];
    const float* gamma_n = (const float*)d_in[9];
    const float* beta_n  = (const float*)d_in[10];
    const float* Watt    = (const float*)d_in[11];
    const float* batt    = (const float*)d_in[12];
    const float* aatt    = (const float*)d_in[13];
    const float* Wk      = (const float*)d_in[14];
    const float* Wr      = (const float*)d_in[15];
    const float* gbias   = (const float*)d_in[16];

    float* out_node = (float*)d_out;
    float* out_edge = out_node + (size_t)NN * UU;

    char* wp = (char*)d_ws;
    auto alloc = [&](size_t bytes) {
        void* p = (void*)wp;
        wp += (bytes + 255) / 256 * 256;
        return p;
    };
    float* z       = (float*)alloc((size_t)NN * 1024 * 4);   // aliased: eattr_bf first, z after
    float* ebuf    = (float*)alloc((size_t)EE * 128 * 4);
    float* s_src   = (float*)alloc((size_t)NN * 8 * 4);
    float* s_dst   = (float*)alloc((size_t)NN * 8 * 4);
    float* s_edge  = (float*)alloc((size_t)EE * 8 * 4);
    float* part_e  = (float*)alloc((size_t)5000 * 256 * 4);
    float* part_n  = (float*)alloc((size_t)313 * 256 * 4);
    float* scale_e = (float*)alloc(512);
    float* shift_e = (float*)alloc(512);
    float* scale_n = (float*)alloc(512);
    float* shift_n = (float*)alloc(512);
    float* attend  = (float*)alloc((size_t)NN * 128 * 4);
    float* nupd    = (float*)alloc((size_t)NN * 128 * 4);
    int*   cnt     = (int*)alloc((size_t)NN * 4);
    int*   offs    = (int*)alloc((size_t)(NN + 1) * 4);
    int*   cursor  = (int*)alloc((size_t)NN * 4);
    int*   elist   = (int*)alloc((size_t)EE * 4);
    unsigned short* node_bf = (unsigned short*)alloc((size_t)NN * 128 * 2);
    unsigned short* Wt      = (unsigned short*)alloc((size_t)128 * 384 * 2);
    unsigned short* eattr_bf = (unsigned short*)z;   // alias: dead before k_z runs

    hipMemsetAsync(cnt, 0, (size_t)NN * 4, stream);
    k_hist<<<(EE + 255) / 256, 256, 0, stream>>>(eidx, cnt, EE);
    k_scan<<<1, 1024, 0, stream>>>(cnt, offs, cursor, NN);
    k_scatter<<<(EE + 255) / 256, 256, 0, stream>>>(eidx, cursor, elist, EE);

    // bf16 conversions for the edge GEMM
    k_f2bf<<<1280, 256, 0, stream>>>(node, node_bf, (long)NN * 128 / 4);
    k_f2bf<<<2048, 256, 0, stream>>>(eattr, eattr_bf, (long)EE * 128 / 4);
    k_wt<<<(384 * 128 + 255) / 256, 256, 0, stream>>>(We, Wt);

    // edge pipeline (uses eattr_bf which aliases z; must precede k_z)
    k_edge_mlp_mfma<<<EE / 64, 256, 0, stream>>>(node_bf, eattr_bf, eidx, Wt, be, ebuf, part_e);
    k_bn_fin<<<128, 256, 0, stream>>>(part_e, EE / 64, 1.f / (float)EE,
                                      gamma_e, beta_e, scale_e, shift_e);
    k_edge_final<<<EE, 128, 0, stream>>>(ebuf, scale_e, shift_e, aatt, out_edge, s_edge);

    // node/attention pipeline
    k_z<<<(NN + 31) / 32, 256, 0, stream>>>(node, Watt, batt, z, NN);
    k_snodes<<<NN, 128, 0, stream>>>(z, aatt, s_src, s_dst, NN);
    k_agg<<<NN, 128, 0, stream>>>(z, s_src, s_dst, s_edge, offs, elist, eidx, attend);

    k_node_mlp<<<(NN + 31) / 32, 256, 0, stream>>>(node, Wn, bnb, nupd, part_n, NN);
    k_bn_fin<<<128, 256, 0, stream>>>(part_n, (NN + 31) / 32, 1.f / (float)NN,
                                      gamma_n, beta_n, scale_n, shift_n);
    k_gru<<<NN / 16, 128, 0, stream>>>(attend, nupd, scale_n, shift_n, Wk, Wr, gbias, out_node);
}

// Round 3
// 552.099 us; speedup vs baseline: 2.0314x; 1.3679x over previous
//
#include <hip/hip_runtime.h>
#include <hip/hip_bf16.h>

#define NN 10000
#define EE 160000
#define FF 128
#define UU 128
#define HH 8
#define BN_EPS 1e-3f

typedef __attribute__((ext_vector_type(8))) short bf16x8;
typedef __attribute__((ext_vector_type(4))) float f32x4;

static __device__ __forceinline__ unsigned short f2bf(float f) {
    unsigned u = __float_as_uint(f);
    u += 0x7fffu + ((u >> 16) & 1u);
    return (unsigned short)(u >> 16);
}
static __device__ __forceinline__ float bf2f(unsigned short b) {
    return __uint_as_float((unsigned)b << 16);
}

// ---------------- f32 -> bf16 bulk convert (count divisible by 4) ----------------
__global__ void k_f2bf(const float* __restrict__ in, unsigned short* __restrict__ out, long n4) {
    long i = (long)blockIdx.x * 256 + threadIdx.x;
    long stride = (long)gridDim.x * 256;
    for (; i < n4; i += stride) {
        float4 v = reinterpret_cast<const float4*>(in)[i];
        ushort4 o;
        o.x = f2bf(v.x); o.y = f2bf(v.y); o.z = f2bf(v.z); o.w = f2bf(v.w);
        reinterpret_cast<ushort4*>(out)[i] = o;
    }
}

// ---------------- W_edge [384][128] f32 -> W^T [128][384] bf16 ----------------
__global__ void k_wt(const float* __restrict__ W, unsigned short* __restrict__ Wt) {
    int i = blockIdx.x * 256 + threadIdx.x;   // i over 384*128
    if (i < 384 * 128) {
        int k = i >> 7, u = i & 127;
        Wt[u * 384 + k] = f2bf(W[i]);
    }
}

// ---------------- CSR construction ----------------
__global__ void k_hist(const int* __restrict__ eidx, int* __restrict__ cnt, int E) {
    int e = blockIdx.x * 256 + threadIdx.x;
    if (e < E) atomicAdd(&cnt[eidx[2 * e]], 1);   // dst = eidx[e][0]
}

__global__ void k_scan(const int* __restrict__ cnt, int* __restrict__ off,
                       int* __restrict__ cursor, int N) {
    __shared__ int s[1024];
    int t = threadIdx.x;
    int run = 0;
    if (t == 0) off[0] = 0;
    for (int base = 0; base < N; base += 1024) {
        int x = (base + t < N) ? cnt[base + t] : 0;
        s[t] = x;
        __syncthreads();
        for (int o = 1; o < 1024; o <<= 1) {
            int v = (t >= o) ? s[t - o] : 0;
            __syncthreads();
            s[t] += v;
            __syncthreads();
        }
        if (base + t < N) {
            off[base + t + 1] = run + s[t];
            cursor[base + t] = run + s[t] - x;
        }
        run += s[1023];
        __syncthreads();
    }
}

__global__ void k_scatter(const int* __restrict__ eidx, int* __restrict__ cursor,
                          int* __restrict__ elist, int E) {
    int e = blockIdx.x * 256 + threadIdx.x;
    if (e < E) {
        int d = eidx[2 * e];
        int p = atomicAdd(&cursor[d], 1);
        elist[p] = e;
    }
}

// ---------------- z = einsum('nf,hfu->hnu') + b_att, stored (N,H,U) ----------------
__global__ void k_z(const float* __restrict__ node, const float* __restrict__ Watt,
                    const float* __restrict__ batt, float* __restrict__ z, int N) {
    __shared__ float ash[32][128];
    int n0 = blockIdx.x * 32;
    int t = threadIdx.x;              // 256
    for (int q = t; q < 32 * 128; q += 256) {
        int m = q >> 7, c = q & 127;
        int n = n0 + m;
        ash[m][c] = (n < N) ? node[(size_t)n * 128 + c] : 0.f;
    }
    __syncthreads();
    int u = t & 127, g = t >> 7;      // g in {0,1}; rows g*16..g*16+15
    for (int h = 0; h < HH; ++h) {
        float acc[16];
        float b = batt[h * 128 + u];
#pragma unroll
        for (int m = 0; m < 16; ++m) acc[m] = b;
        const float* W = Watt + (size_t)h * 128 * 128 + u;
        for (int f = 0; f < 128; f += 4) {
            float w0 = W[(f + 0) * 128], w1 = W[(f + 1) * 128];
            float w2 = W[(f + 2) * 128], w3 = W[(f + 3) * 128];
#pragma unroll
            for (int m = 0; m < 16; ++m) {
                const float4 a = *reinterpret_cast<const float4*>(&ash[g * 16 + m][f]);
                acc[m] = fmaf(a.x, w0, acc[m]);
                acc[m] = fmaf(a.y, w1, acc[m]);
                acc[m] = fmaf(a.z, w2, acc[m]);
                acc[m] = fmaf(a.w, w3, acc[m]);
            }
        }
#pragma unroll
        for (int m = 0; m < 16; ++m) {
            int n = n0 + g * 16 + m;
            if (n < N) z[(size_t)n * 1024 + h * 128 + u] = acc[m];
        }
    }
}

// ---------------- s_src[n,h], s_dst[n,h]: wave=node, lane=(head, 16-col slice) ----------------
__global__ void __launch_bounds__(256) k_snodes(
        const float* __restrict__ z, const float* __restrict__ aatt,
        float* __restrict__ s_src, float* __restrict__ s_dst, int N) {
    int t = threadIdx.x;
    int w = t >> 6, lane = t & 63;
    int n = blockIdx.x * 4 + w;
    if (n >= N) return;
    int h = lane >> 3, p = lane & 7;
    const float* zp = z + (size_t)n * 1024 + h * 128 + p * 16;
    const float* as = aatt + h * 384 + p * 16;
    float vs = 0.f, vd = 0.f;
#pragma unroll
    for (int j = 0; j < 4; ++j) {
        float4 zv = *reinterpret_cast<const float4*>(zp + j * 4);
        float4 av = *reinterpret_cast<const float4*>(as + j * 4);
        float4 dv = *reinterpret_cast<const float4*>(as + 128 + j * 4);
        vs += zv.x * av.x + zv.y * av.y + zv.z * av.z + zv.w * av.w;
        vd += zv.x * dv.x + zv.y * dv.y + zv.z * dv.z + zv.w * dv.w;
    }
#pragma unroll
    for (int o = 1; o < 8; o <<= 1) {
        vs += __shfl_xor(vs, o, 64);
        vd += __shfl_xor(vd, o, 64);
    }
    if (p == 0) {
        s_src[n * 8 + h] = vs;
        s_dst[n * 8 + h] = vd;
    }
}

// ---------------- edge MLP via MFMA bf16: relu(concat @ W_edge + b), BN partials ----------------
// 64 edges x 128 outputs per block, 4 waves (2x2), mfma_f32_16x16x32_bf16. ebuf stored bf16.
__global__ void __launch_bounds__(256) k_edge_mlp_mfma(
        const unsigned short* __restrict__ node_bf, const unsigned short* __restrict__ eattr_bf,
        const int* __restrict__ eidx, const unsigned short* __restrict__ Wt,
        const float* __restrict__ be, unsigned short* __restrict__ ebuf, float* __restrict__ part) {
    __shared__ unsigned short ash[64][392];     // 384 + 8 pad -> 784B row stride
    __shared__ int sd[128];
    __shared__ float sbuf[4][64], qbuf[4][64];
    int e0 = blockIdx.x * 64;
    int t = threadIdx.x;
    if (t < 128) sd[t] = eidx[e0 * 2 + t];      // [e][0]=dst, [e][1]=src
    __syncthreads();
    // gather 64 rows x 48 16B-chunks
    for (int q = t; q < 64 * 48; q += 256) {
        int r = q / 48, c = q - r * 48;
        const unsigned short* sp;
        if (c < 16)      sp = node_bf + (size_t)sd[r * 2 + 1] * 128 + c * 8;
        else if (c < 32) sp = node_bf + (size_t)sd[r * 2] * 128 + (c - 16) * 8;
        else             sp = eattr_bf + (size_t)(e0 + r) * 128 + (c - 32) * 8;
        *reinterpret_cast<uint4*>(&ash[r][c * 8]) = *reinterpret_cast<const uint4*>(sp);
    }
    __syncthreads();

    int wid = t >> 6, lane = t & 63;
    int wm = wid >> 1, wn = wid & 1;
    int lr = lane & 15, lg = lane >> 4;

    f32x4 acc[2][4];
#pragma unroll
    for (int m = 0; m < 2; ++m)
#pragma unroll
        for (int n = 0; n < 4; ++n) acc[m][n] = (f32x4){0.f, 0.f, 0.f, 0.f};

#pragma unroll
    for (int ks = 0; ks < 12; ++ks) {
        int kb = ks * 32 + lg * 8;
        bf16x8 a0 = *reinterpret_cast<const bf16x8*>(&ash[wm * 32 + lr][kb]);
        bf16x8 a1 = *reinterpret_cast<const bf16x8*>(&ash[wm * 32 + 16 + lr][kb]);
        bf16x8 b[4];
#pragma unroll
        for (int n = 0; n < 4; ++n)
            b[n] = *reinterpret_cast<const bf16x8*>(Wt + (size_t)(wn * 64 + n * 16 + lr) * 384 + kb);
#pragma unroll
        for (int n = 0; n < 4; ++n) {
            acc[0][n] = __builtin_amdgcn_mfma_f32_16x16x32_bf16(a0, b[n], acc[0][n], 0, 0, 0);
            acc[1][n] = __builtin_amdgcn_mfma_f32_16x16x32_bf16(a1, b[n], acc[1][n], 0, 0, 0);
        }
    }

    // epilogue: bias + relu + store bf16 + per-column BN partials (f32, exact)
    float s[4] = {0.f, 0.f, 0.f, 0.f}, q[4] = {0.f, 0.f, 0.f, 0.f};
#pragma unroll
    for (int n = 0; n < 4; ++n) {
        int col = wn * 64 + n * 16 + lr;
        float bias = be[col];
#pragma unroll
        for (int m = 0; m < 2; ++m) {
            int rowb = wm * 32 + m * 16 + lg * 4;
#pragma unroll
            for (int r = 0; r < 4; ++r) {
                float v = acc[m][n][r] + bias;
                v = v > 0.f ? v : 0.f;
                ebuf[(size_t)(e0 + rowb + r) * 128 + col] = f2bf(v);
                s[n] += v;
                q[n] += v * v;
            }
        }
    }
#pragma unroll
    for (int n = 0; n < 4; ++n) {
        s[n] += __shfl_xor(s[n], 16, 64);
        s[n] += __shfl_xor(s[n], 32, 64);
        q[n] += __shfl_xor(q[n], 16, 64);
        q[n] += __shfl_xor(q[n], 32, 64);
    }
    if (lane < 16) {
#pragma unroll
        for (int n = 0; n < 4; ++n) {
            sbuf[wid][n * 16 + lane] = s[n];
            qbuf[wid][n * 16 + lane] = q[n];
        }
    }
    __syncthreads();
    if (t < 128) {
        int half = t >> 6, c = t & 63;
        part[(size_t)blockIdx.x * 256 + t] = sbuf[half][c] + sbuf[2 + half][c];
        part[(size_t)blockIdx.x * 256 + 128 + t] = qbuf[half][c] + qbuf[2 + half][c];
    }
}

// ---------------- BN finalize: scale/shift per column ----------------
__global__ void k_bn_fin(const float* __restrict__ part, int nblk, float invcnt,
                         const float* __restrict__ g, const float* __restrict__ b,
                         float* __restrict__ scale, float* __restrict__ shift) {
    int u = blockIdx.x;               // 128 blocks
    int t = threadIdx.x;              // 256
    float s = 0.f, q = 0.f;
    for (int i = t; i < nblk; i += 256) {
        s += part[(size_t)i * 256 + u];
        q += part[(size_t)i * 256 + 128 + u];
    }
    __shared__ float ls[4], lq[4];
    for (int o = 32; o > 0; o >>= 1) {
        s += __shfl_down(s, o, 64);
        q += __shfl_down(q, o, 64);
    }
    int lane = t & 63, w = t >> 6;
    if (lane == 0) { ls[w] = s; lq[w] = q; }
    __syncthreads();
    if (t == 0) {
        float S = ls[0] + ls[1] + ls[2] + ls[3];
        float Q = lq[0] + lq[1] + lq[2] + lq[3];
        float mean = S * invcnt;
        float var = Q * invcnt - mean * mean;
        float inv = rsqrtf(var + BN_EPS);
        float sc = g[u] * inv;
        scale[u] = sc;
        shift[u] = b[u] - mean * sc;
    }
}

// ---------------- edge finalize: wave=2 edges, lane=4 cols; BN apply + s_edge ----------------
__global__ void __launch_bounds__(256) k_edge_final(
        const unsigned short* __restrict__ ebuf, const float* __restrict__ scale,
        const float* __restrict__ shift, const float* __restrict__ aatt,
        float* __restrict__ eout, float* __restrict__ s_edge) {
    int t = threadIdx.x;
    int w = t >> 6, lane = t & 63;
    int q = lane & 31, half = lane >> 5;
    int e = blockIdx.x * 8 + w * 2 + half;

    float4 sc = *reinterpret_cast<const float4*>(scale + q * 4);
    float4 sh = *reinterpret_cast<const float4*>(shift + q * 4);
    float4 a4[8];
#pragma unroll
    for (int h = 0; h < 8; ++h)
        a4[h] = *reinterpret_cast<const float4*>(aatt + h * 384 + 256 + q * 4);

    ushort4 xb = *reinterpret_cast<const ushort4*>(ebuf + (size_t)e * 128 + q * 4);
    float4 x;
    x.x = bf2f(xb.x) * sc.x + sh.x;
    x.y = bf2f(xb.y) * sc.y + sh.y;
    x.z = bf2f(xb.z) * sc.z + sh.z;
    x.w = bf2f(xb.w) * sc.w + sh.w;
    *reinterpret_cast<float4*>(eout + (size_t)e * 128 + q * 4) = x;

    float v[8];
#pragma unroll
    for (int h = 0; h < 8; ++h)
        v[h] = x.x * a4[h].x + x.y * a4[h].y + x.z * a4[h].z + x.w * a4[h].w;
#pragma unroll
    for (int o = 1; o < 32; o <<= 1) {
#pragma unroll
        for (int h = 0; h < 8; ++h) v[h] += __shfl_xor(v[h], o, 64);
    }
    if (q == 0) {
#pragma unroll
        for (int h = 0; h < 8; ++h) s_edge[e * 8 + h] = v[h];
    }
}

// ---------------- attention softmax + aggregation (per dst node, all heads) ----------------
__global__ void k_agg(const float* __restrict__ z, const float* __restrict__ s_src,
                      const float* __restrict__ s_dst, const float* __restrict__ s_edge,
                      const int* __restrict__ off, const int* __restrict__ elist,
                      const int* __restrict__ eidx, float* __restrict__ att) {
    int n = blockIdx.x;
    int t = threadIdx.x;              // 128
    int beg = off[n], end = off[n + 1];
    int deg = end - beg;
    if (deg == 0) { att[(size_t)n * 128 + t] = 0.f; return; }

    float sdh[8];
#pragma unroll
    for (int h = 0; h < 8; ++h) sdh[h] = s_dst[n * 8 + h];

    __shared__ float lred[16];
    __shared__ float wbuf[128][8];
    __shared__ int snbuf[128];

    float mx[8], den[8];
#pragma unroll
    for (int h = 0; h < 8; ++h) { mx[h] = -1e30f; den[h] = 0.f; }

    int lane = t & 63, w = t >> 6;

    // pass 1: running max / denominator (online across chunks of 128)
    for (int c0 = 0; c0 < deg; c0 += 128) {
        int cn = min(128, deg - c0);
        bool act = t < cn;
        int e = 0, sn = 0;
        if (act) { e = elist[beg + c0 + t]; sn = eidx[2 * e + 1]; }
        float lg[8];
#pragma unroll
        for (int h = 0; h < 8; ++h) {
            float x = act ? (s_src[sn * 8 + h] + sdh[h] + s_edge[e * 8 + h]) : -1e30f;
            lg[h] = x >= 0.f ? x : 0.2f * x;
        }
        float cm[8];
#pragma unroll
        for (int h = 0; h < 8; ++h) cm[h] = lg[h];
        for (int o = 32; o > 0; o >>= 1) {
#pragma unroll
            for (int h = 0; h < 8; ++h) cm[h] = fmaxf(cm[h], __shfl_down(cm[h], o, 64));
        }
        if (lane == 0) {
#pragma unroll
            for (int h = 0; h < 8; ++h) lred[w * 8 + h] = cm[h];
        }
        __syncthreads();
#pragma unroll
        for (int h = 0; h < 8; ++h) cm[h] = fmaxf(lred[h], lred[8 + h]);
        __syncthreads();
        float cs[8];
#pragma unroll
        for (int h = 0; h < 8; ++h) cs[h] = act ? __expf(lg[h] - cm[h]) : 0.f;
        for (int o = 32; o > 0; o >>= 1) {
#pragma unroll
            for (int h = 0; h < 8; ++h) cs[h] += __shfl_down(cs[h], o, 64);
        }
        if (lane == 0) {
#pragma unroll
            for (int h = 0; h < 8; ++h) lred[w * 8 + h] = cs[h];
        }
        __syncthreads();
#pragma unroll
        for (int h = 0; h < 8; ++h) {
            float csum = lred[h] + lred[8 + h];
            float nm = fmaxf(mx[h], cm[h]);
            den[h] = den[h] * __expf(mx[h] - nm) + csum * __expf(cm[h] - nm);
            mx[h] = nm;
        }
        __syncthreads();
    }
    float inv[8];
#pragma unroll
    for (int h = 0; h < 8; ++h) inv[h] = 1.f / den[h];

    // pass 2: weights into LDS, then accumulate sum over heads of alpha*z[src]
    float acc = 0.f;
    for (int c0 = 0; c0 < deg; c0 += 128) {
        int cn = min(128, deg - c0);
        if (t < cn) {
            int e = elist[beg + c0 + t];
            int sn = eidx[2 * e + 1];
            snbuf[t] = sn;
#pragma unroll
            for (int h = 0; h < 8; ++h) {
                float x = s_src[sn * 8 + h] + sdh[h] + s_edge[e * 8 + h];
                x = x >= 0.f ? x : 0.2f * x;
                wbuf[t][h] = __expf(x - mx[h]) * inv[h];
            }
        }
        __syncthreads();
        for (int i = 0; i < cn; ++i) {
            int sn = snbuf[i];
            const float* zr = z + (size_t)sn * 1024 + t;
#pragma unroll
            for (int h = 0; h < 8; ++h)
                acc = fmaf(wbuf[i][h], zr[h * 128], acc);
        }
        __syncthreads();
    }
    att[(size_t)n * 128 + t] = fmaxf(acc * 0.125f, 0.f);
}

// ---------------- node MLP: relu(node @ W_node + b), partial BN stats ----------------
__global__ void k_node_mlp(const float* __restrict__ node, const float* __restrict__ Wn,
                           const float* __restrict__ bn, float* __restrict__ nupd,
                           float* __restrict__ part, int N) {
    __shared__ float ash[32][128];
    int n0 = blockIdx.x * 32;
    int t = threadIdx.x;              // 256
    for (int q = t; q < 32 * 128; q += 256) {
        int m = q >> 7, c = q & 127;
        int n = n0 + m;
        ash[m][c] = (n < N) ? node[(size_t)n * 128 + c] : 0.f;
    }
    __syncthreads();
    int u = t & 127, g = t >> 7;
    float acc[16];
    float b = bn[u];
#pragma unroll
    for (int m = 0; m < 16; ++m) acc[m] = b;
    const float* W = Wn + u;
    for (int f = 0; f < 128; f += 4) {
        float w0 = W[(f + 0) * 128], w1 = W[(f + 1) * 128];
        float w2 = W[(f + 2) * 128], w3 = W[(f + 3) * 128];
#pragma unroll
        for (int m = 0; m < 16; ++m) {
            const float4 a = *reinterpret_cast<const float4*>(&ash[g * 16 + m][f]);
            acc[m] = fmaf(a.x, w0, acc[m]);
            acc[m] = fmaf(a.y, w1, acc[m]);
            acc[m] = fmaf(a.z, w2, acc[m]);
            acc[m] = fmaf(a.w, w3, acc[m]);
        }
    }
    float ls = 0.f, lq = 0.f;
#pragma unroll
    for (int m = 0; m < 16; ++m) {
        int n = n0 + g * 16 + m;
        float r = acc[m] > 0.f ? acc[m] : 0.f;
        if (n < N) {
            nupd[(size_t)n * 128 + u] = r;
            ls += r;
            lq += r * r;
        }
    }
    __syncthreads();
    float* red = (float*)ash;
    red[t] = ls;
    red[256 + t] = lq;
    __syncthreads();
    if (g == 0) {
        part[(size_t)blockIdx.x * 256 + u] = red[u] + red[128 + u];
        part[(size_t)blockIdx.x * 256 + 128 + u] = red[256 + u] + red[256 + 128 + u];
    }
}

// ---------------- GRU combine ----------------
__global__ void k_gru(const float* __restrict__ att, const float* __restrict__ nupd,
                      const float* __restrict__ scale, const float* __restrict__ shift,
                      const float* __restrict__ Wk, const float* __restrict__ Wr,
                      const float* __restrict__ gbias, float* __restrict__ outp) {
    __shared__ float ash[16][128];
    __shared__ float ush[16][128];
    __shared__ float zg[16][128];
    __shared__ float rg[16][128];
    int n0 = blockIdx.x * 16;
    int t = threadIdx.x;              // 128
    for (int m = 0; m < 16; ++m) {
        ash[m][t] = att[(size_t)(n0 + m) * 128 + t];
        ush[m][t] = nupd[(size_t)(n0 + m) * 128 + t] * scale[t] + shift[t];
    }
    __syncthreads();
    for (int c = 0; c < 3; ++c) {
        float ax[16], ar[16];
        float bx = gbias[c * 128 + t];
        float br = gbias[384 + c * 128 + t];
#pragma unroll
        for (int m = 0; m < 16; ++m) { ax[m] = bx; ar[m] = br; }
        const float* wkp = Wk + c * 128 + t;
        const float* wrp = Wr + c * 128 + t;
        for (int uu = 0; uu < 128; uu += 4) {
            float wk0 = wkp[(uu + 0) * 384], wk1 = wkp[(uu + 1) * 384];
            float wk2 = wkp[(uu + 2) * 384], wk3 = wkp[(uu + 3) * 384];
            float wr0 = wrp[(uu + 0) * 384], wr1 = wrp[(uu + 1) * 384];
            float wr2 = wrp[(uu + 2) * 384], wr3 = wrp[(uu + 3) * 384];
#pragma unroll
            for (int m = 0; m < 16; ++m) {
                const float4 av = *reinterpret_cast<const float4*>(&ash[m][uu]);
                const float4 uv = *reinterpret_cast<const float4*>(&ush[m][uu]);
                ax[m] = fmaf(av.x, wk0, ax[m]); ax[m] = fmaf(av.y, wk1, ax[m]);
                ax[m] = fmaf(av.z, wk2, ax[m]); ax[m] = fmaf(av.w, wk3, ax[m]);
                ar[m] = fmaf(uv.x, wr0, ar[m]); ar[m] = fmaf(uv.y, wr1, ar[m]);
                ar[m] = fmaf(uv.z, wr2, ar[m]); ar[m] = fmaf(uv.w, wr3, ar[m]);
            }
        }
        if (c == 0) {
#pragma unroll
            for (int m = 0; m < 16; ++m)
                zg[m][t] = 1.f / (1.f + __expf(-(ax[m] + ar[m])));
        } else if (c == 1) {
#pragma unroll
            for (int m = 0; m < 16; ++m)
                rg[m][t] = 1.f / (1.f + __expf(-(ax[m] + ar[m])));
        } else {
#pragma unroll
            for (int m = 0; m < 16; ++m) {
                float hh = tanhf(ax[m] + rg[m][t] * ar[m]);
                float zv = zg[m][t];
                outp[(size_t)(n0 + m) * 128 + t] = zv * ush[m][t] + (1.f - zv) * hh;
            }
        }
    }
}

// ---------------- launch ----------------
extern "C" void kernel_launch(void* const* d_in, const int* in_sizes, int n_in,
                              void* d_out, int out_size, void* d_ws, size_t ws_size,
                              hipStream_t stream) {
    const float* node    = (const float*)d_in[0];
    const float* eattr   = (const float*)d_in[1];
    const int*   eidx    = (const int*)d_in[2];
    const float* We      = (const float*)d_in[3];
    const float* be      = (const float*)d_in[4];
    const float* gamma_e = (const float*)d_in[5];
    const float* beta_e  = (const float*)d_in[6];
    const float* Wn      = (const float*)d_in[7];
    const float* bnb     = (const float*)d_in[8];
    const float* gamma_n = (const float*)d_in[9];
    const float* beta_n  = (const float*)d_in[10];
    const float* Watt    = (const float*)d_in[11];
    const float* batt    = (const float*)d_in[12];
    const float* aatt    = (const float*)d_in[13];
    const float* Wk      = (const float*)d_in[14];
    const float* Wr      = (const float*)d_in[15];
    const float* gbias   = (const float*)d_in[16];

    float* out_node = (float*)d_out;
    float* out_edge = out_node + (size_t)NN * UU;

    char* wp = (char*)d_ws;
    auto alloc = [&](size_t bytes) {
        void* p = (void*)wp;
        wp += (bytes + 255) / 256 * 256;
        return p;
    };
    float* z       = (float*)alloc((size_t)NN * 1024 * 4);   // aliased: eattr_bf first, z after
    unsigned short* ebuf = (unsigned short*)alloc((size_t)EE * 128 * 2);
    float* s_src   = (float*)alloc((size_t)NN * 8 * 4);
    float* s_dst   = (float*)alloc((size_t)NN * 8 * 4);
    float* s_edge  = (float*)alloc((size_t)EE * 8 * 4);
    float* part_e  = (float*)alloc((size_t)2500 * 256 * 4);
    float* part_n  = (float*)alloc((size_t)313 * 256 * 4);
    float* scale_e = (float*)alloc(512);
    float* shift_e = (float*)alloc(512);
    float* scale_n = (float*)alloc(512);
    float* shift_n = (float*)alloc(512);
    float* attend  = (float*)alloc((size_t)NN * 128 * 4);
    float* nupd    = (float*)alloc((size_t)NN * 128 * 4);
    int*   cnt     = (int*)alloc((size_t)NN * 4);
    int*   offs    = (int*)alloc((size_t)(NN + 1) * 4);
    int*   cursor  = (int*)alloc((size_t)NN * 4);
    int*   elist   = (int*)alloc((size_t)EE * 4);
    unsigned short* node_bf = (unsigned short*)alloc((size_t)NN * 128 * 2);
    unsigned short* Wt      = (unsigned short*)alloc((size_t)128 * 384 * 2);
    unsigned short* eattr_bf = (unsigned short*)z;   // alias: dead before k_z runs

    hipMemsetAsync(cnt, 0, (size_t)NN * 4, stream);
    k_hist<<<(EE + 255) / 256, 256, 0, stream>>>(eidx, cnt, EE);
    k_scan<<<1, 1024, 0, stream>>>(cnt, offs, cursor, NN);
    k_scatter<<<(EE + 255) / 256, 256, 0, stream>>>(eidx, cursor, elist, EE);

    // bf16 conversions for the edge GEMM
    k_f2bf<<<1280, 256, 0, stream>>>(node, node_bf, (long)NN * 128 / 4);
    k_f2bf<<<2048, 256, 0, stream>>>(eattr, eattr_bf, (long)EE * 128 / 4);
    k_wt<<<(384 * 128 + 255) / 256, 256, 0, stream>>>(We, Wt);

    // edge pipeline (uses eattr_bf which aliases z; must precede k_z)
    k_edge_mlp_mfma<<<EE / 64, 256, 0, stream>>>(node_bf, eattr_bf, eidx, Wt, be, ebuf, part_e);
    k_bn_fin<<<128, 256, 0, stream>>>(part_e, EE / 64, 1.f / (float)EE,
                                      gamma_e, beta_e, scale_e, shift_e);
    k_edge_final<<<EE / 8, 256, 0, stream>>>(ebuf, scale_e, shift_e, aatt, out_edge, s_edge);

    // node/attention pipeline
    k_z<<<(NN + 31) / 32, 256, 0, stream>>>(node, Watt, batt, z, NN);
    k_snodes<<<NN / 4, 256, 0, stream>>>(z, aatt, s_src, s_dst, NN);
    k_agg<<<NN, 128, 0, stream>>>(z, s_src, s_dst, s_edge, offs, elist, eidx, attend);

    k_node_mlp<<<(NN + 31) / 32, 256, 0, stream>>>(node, Wn, bnb, nupd, part_n, NN);
    k_bn_fin<<<128, 256, 0, stream>>>(part_n, (NN + 31) / 32, 1.f / (float)NN,
                                      gamma_n, beta_n, scale_n, shift_n);
    k_gru<<<NN / 16, 128, 0, stream>>>(attend, nupd, scale_n, shift_n, Wk, Wr, gbias, out_node);
}

// Round 4
// 429.452 us; speedup vs baseline: 2.6115x; 1.2856x over previous
//
#include <hip/hip_runtime.h>
#include <hip/hip_bf16.h>

#define NN 10000
#define EE 160000
#define FF 128
#define UU 128
#define HH 8
#define BN_EPS 1e-3f

typedef __attribute__((ext_vector_type(8))) short bf16x8;
typedef __attribute__((ext_vector_type(8))) unsigned short u16x8;
typedef __attribute__((ext_vector_type(4))) float f32x4;

static __device__ __forceinline__ unsigned short f2bf(float f) {
    unsigned u = __float_as_uint(f);
    u += 0x7fffu + ((u >> 16) & 1u);
    return (unsigned short)(u >> 16);
}
static __device__ __forceinline__ float bf2f(unsigned short b) {
    return __uint_as_float((unsigned)b << 16);
}

// ---------------- f32 -> bf16 bulk convert (count divisible by 4) ----------------
__global__ void k_f2bf(const float* __restrict__ in, unsigned short* __restrict__ out, long n4) {
    long i = (long)blockIdx.x * 256 + threadIdx.x;
    long stride = (long)gridDim.x * 256;
    for (; i < n4; i += stride) {
        float4 v = reinterpret_cast<const float4*>(in)[i];
        ushort4 o;
        o.x = f2bf(v.x); o.y = f2bf(v.y); o.z = f2bf(v.z); o.w = f2bf(v.w);
        reinterpret_cast<ushort4*>(out)[i] = o;
    }
}

// ---------------- W_edge [384][128] f32 -> W^T [128][384] bf16 ----------------
__global__ void k_wt(const float* __restrict__ W, unsigned short* __restrict__ Wt) {
    int i = blockIdx.x * 256 + threadIdx.x;   // i over 384*128
    if (i < 384 * 128) {
        int k = i >> 7, u = i & 127;
        Wt[u * 384 + k] = f2bf(W[i]);
    }
}

// ---------------- W_att [8][128][128] f32 -> per-head W^T [8][128][128] bf16 ----------------
__global__ void k_wt_att(const float* __restrict__ W, unsigned short* __restrict__ Wt) {
    int i = blockIdx.x * 256 + threadIdx.x;   // over 8*128*128
    if (i < 8 * 128 * 128) {
        int h = i >> 14, rem = i & 16383, f = rem >> 7, u = rem & 127;
        Wt[h * 16384 + u * 128 + f] = f2bf(W[i]);
    }
}

// ---------------- CSR construction ----------------
__global__ void k_hist(const int* __restrict__ eidx, int* __restrict__ cnt, int E) {
    int e = blockIdx.x * 256 + threadIdx.x;
    if (e < E) atomicAdd(&cnt[eidx[2 * e]], 1);   // dst = eidx[e][0]
}

__global__ void k_scan(const int* __restrict__ cnt, int* __restrict__ off,
                       int* __restrict__ cursor, int N) {
    __shared__ int s[1024];
    int t = threadIdx.x;
    int run = 0;
    if (t == 0) off[0] = 0;
    for (int base = 0; base < N; base += 1024) {
        int x = (base + t < N) ? cnt[base + t] : 0;
        s[t] = x;
        __syncthreads();
        for (int o = 1; o < 1024; o <<= 1) {
            int v = (t >= o) ? s[t - o] : 0;
            __syncthreads();
            s[t] += v;
            __syncthreads();
        }
        if (base + t < N) {
            off[base + t + 1] = run + s[t];
            cursor[base + t] = run + s[t] - x;
        }
        run += s[1023];
        __syncthreads();
    }
}

__global__ void k_scatter(const int* __restrict__ eidx, int* __restrict__ cursor,
                          int* __restrict__ elist, int E) {
    int e = blockIdx.x * 256 + threadIdx.x;
    if (e < E) {
        int d = eidx[2 * e];
        int p = atomicAdd(&cursor[d], 1);
        elist[p] = e;
    }
}

// ---------------- z (bf16) = node @ W_att[h] + b_att[h], MFMA, stored (N,H,U) ----------------
__global__ void __launch_bounds__(256) k_z_mfma(
        const unsigned short* __restrict__ node_bf, const unsigned short* __restrict__ WtA,
        const float* __restrict__ batt, unsigned short* __restrict__ zbf, int N) {
    __shared__ unsigned short ash[64][136];     // 128 + 8 pad
    int n0 = blockIdx.x * 64;
    int h = blockIdx.y;
    int t = threadIdx.x;
    for (int q = t; q < 64 * 16; q += 256) {
        int r = q >> 4, c = q & 15;
        int n = n0 + r; if (n >= N) n = N - 1;
        *reinterpret_cast<uint4*>(&ash[r][c * 8]) =
            *reinterpret_cast<const uint4*>(node_bf + (size_t)n * 128 + c * 8);
    }
    __syncthreads();

    int wid = t >> 6, lane = t & 63;
    int wm = wid >> 1, wn = wid & 1;
    int lr = lane & 15, lg = lane >> 4;

    f32x4 acc[2][4];
#pragma unroll
    for (int m = 0; m < 2; ++m)
#pragma unroll
        for (int n = 0; n < 4; ++n) acc[m][n] = (f32x4){0.f, 0.f, 0.f, 0.f};

    const unsigned short* Wh = WtA + (size_t)h * 16384;
#pragma unroll
    for (int ks = 0; ks < 4; ++ks) {
        int kb = ks * 32 + lg * 8;
        bf16x8 a0 = *reinterpret_cast<const bf16x8*>(&ash[wm * 32 + lr][kb]);
        bf16x8 a1 = *reinterpret_cast<const bf16x8*>(&ash[wm * 32 + 16 + lr][kb]);
        bf16x8 b[4];
#pragma unroll
        for (int n = 0; n < 4; ++n)
            b[n] = *reinterpret_cast<const bf16x8*>(Wh + (size_t)(wn * 64 + n * 16 + lr) * 128 + kb);
#pragma unroll
        for (int n = 0; n < 4; ++n) {
            acc[0][n] = __builtin_amdgcn_mfma_f32_16x16x32_bf16(a0, b[n], acc[0][n], 0, 0, 0);
            acc[1][n] = __builtin_amdgcn_mfma_f32_16x16x32_bf16(a1, b[n], acc[1][n], 0, 0, 0);
        }
    }

#pragma unroll
    for (int n = 0; n < 4; ++n) {
        int col = wn * 64 + n * 16 + lr;
        float bias = batt[h * 128 + col];
#pragma unroll
        for (int m = 0; m < 2; ++m) {
            int rowb = wm * 32 + m * 16 + lg * 4;
#pragma unroll
            for (int r = 0; r < 4; ++r) {
                int row = n0 + rowb + r;
                if (row < N)
                    zbf[(size_t)row * 1024 + h * 128 + col] = f2bf(acc[m][n][r] + bias);
            }
        }
    }
}

// ---------------- s_src[n,h], s_dst[n,h]: wave=node, lane=(head, 16-col slice) ----------------
__global__ void __launch_bounds__(256) k_snodes(
        const unsigned short* __restrict__ zbf, const float* __restrict__ aatt,
        float* __restrict__ s_src, float* __restrict__ s_dst, int N) {
    int t = threadIdx.x;
    int w = t >> 6, lane = t & 63;
    int n = blockIdx.x * 4 + w;
    if (n >= N) return;
    int h = lane >> 3, p = lane & 7;
    const unsigned short* zp = zbf + (size_t)n * 1024 + h * 128 + p * 16;
    const float* as = aatt + h * 384 + p * 16;
    u16x8 z0 = *reinterpret_cast<const u16x8*>(zp);
    u16x8 z1 = *reinterpret_cast<const u16x8*>(zp + 8);
    float vs = 0.f, vd = 0.f;
#pragma unroll
    for (int j = 0; j < 8; ++j) {
        float zv = bf2f(z0[j]);
        vs = fmaf(zv, as[j], vs);
        vd = fmaf(zv, as[128 + j], vd);
    }
#pragma unroll
    for (int j = 0; j < 8; ++j) {
        float zv = bf2f(z1[j]);
        vs = fmaf(zv, as[8 + j], vs);
        vd = fmaf(zv, as[136 + j], vd);
    }
#pragma unroll
    for (int o = 1; o < 8; o <<= 1) {
        vs += __shfl_xor(vs, o, 64);
        vd += __shfl_xor(vd, o, 64);
    }
    if (p == 0) {
        s_src[n * 8 + h] = vs;
        s_dst[n * 8 + h] = vd;
    }
}

// ---------------- edge MLP via MFMA bf16: relu(concat @ W_edge + b), BN partials ----------------
__global__ void __launch_bounds__(256) k_edge_mlp_mfma(
        const unsigned short* __restrict__ node_bf, const unsigned short* __restrict__ eattr_bf,
        const int* __restrict__ eidx, const unsigned short* __restrict__ Wt,
        const float* __restrict__ be, unsigned short* __restrict__ ebuf, float* __restrict__ part) {
    __shared__ unsigned short ash[64][392];     // 384 + 8 pad
    __shared__ int sd[128];
    __shared__ float sbuf[4][64], qbuf[4][64];
    int e0 = blockIdx.x * 64;
    int t = threadIdx.x;
    if (t < 128) sd[t] = eidx[e0 * 2 + t];      // [e][0]=dst, [e][1]=src
    __syncthreads();
    for (int q = t; q < 64 * 48; q += 256) {
        int r = q / 48, c = q - r * 48;
        const unsigned short* sp;
        if (c < 16)      sp = node_bf + (size_t)sd[r * 2 + 1] * 128 + c * 8;
        else if (c < 32) sp = node_bf + (size_t)sd[r * 2] * 128 + (c - 16) * 8;
        else             sp = eattr_bf + (size_t)(e0 + r) * 128 + (c - 32) * 8;
        *reinterpret_cast<uint4*>(&ash[r][c * 8]) = *reinterpret_cast<const uint4*>(sp);
    }
    __syncthreads();

    int wid = t >> 6, lane = t & 63;
    int wm = wid >> 1, wn = wid & 1;
    int lr = lane & 15, lg = lane >> 4;

    f32x4 acc[2][4];
#pragma unroll
    for (int m = 0; m < 2; ++m)
#pragma unroll
        for (int n = 0; n < 4; ++n) acc[m][n] = (f32x4){0.f, 0.f, 0.f, 0.f};

#pragma unroll
    for (int ks = 0; ks < 12; ++ks) {
        int kb = ks * 32 + lg * 8;
        bf16x8 a0 = *reinterpret_cast<const bf16x8*>(&ash[wm * 32 + lr][kb]);
        bf16x8 a1 = *reinterpret_cast<const bf16x8*>(&ash[wm * 32 + 16 + lr][kb]);
        bf16x8 b[4];
#pragma unroll
        for (int n = 0; n < 4; ++n)
            b[n] = *reinterpret_cast<const bf16x8*>(Wt + (size_t)(wn * 64 + n * 16 + lr) * 384 + kb);
#pragma unroll
        for (int n = 0; n < 4; ++n) {
            acc[0][n] = __builtin_amdgcn_mfma_f32_16x16x32_bf16(a0, b[n], acc[0][n], 0, 0, 0);
            acc[1][n] = __builtin_amdgcn_mfma_f32_16x16x32_bf16(a1, b[n], acc[1][n], 0, 0, 0);
        }
    }

    float s[4] = {0.f, 0.f, 0.f, 0.f}, q[4] = {0.f, 0.f, 0.f, 0.f};
#pragma unroll
    for (int n = 0; n < 4; ++n) {
        int col = wn * 64 + n * 16 + lr;
        float bias = be[col];
#pragma unroll
        for (int m = 0; m < 2; ++m) {
            int rowb = wm * 32 + m * 16 + lg * 4;
#pragma unroll
            for (int r = 0; r < 4; ++r) {
                float v = acc[m][n][r] + bias;
                v = v > 0.f ? v : 0.f;
                ebuf[(size_t)(e0 + rowb + r) * 128 + col] = f2bf(v);
                s[n] += v;
                q[n] += v * v;
            }
        }
    }
#pragma unroll
    for (int n = 0; n < 4; ++n) {
        s[n] += __shfl_xor(s[n], 16, 64);
        s[n] += __shfl_xor(s[n], 32, 64);
        q[n] += __shfl_xor(q[n], 16, 64);
        q[n] += __shfl_xor(q[n], 32, 64);
    }
    if (lane < 16) {
#pragma unroll
        for (int n = 0; n < 4; ++n) {
            sbuf[wid][n * 16 + lane] = s[n];
            qbuf[wid][n * 16 + lane] = q[n];
        }
    }
    __syncthreads();
    if (t < 128) {
        int half = t >> 6, c = t & 63;
        part[(size_t)blockIdx.x * 256 + t] = sbuf[half][c] + sbuf[2 + half][c];
        part[(size_t)blockIdx.x * 256 + 128 + t] = qbuf[half][c] + qbuf[2 + half][c];
    }
}

// ---------------- BN finalize: scale/shift per column ----------------
__global__ void k_bn_fin(const float* __restrict__ part, int nblk, float invcnt,
                         const float* __restrict__ g, const float* __restrict__ b,
                         float* __restrict__ scale, float* __restrict__ shift) {
    int u = blockIdx.x;               // 128 blocks
    int t = threadIdx.x;              // 256
    float s = 0.f, q = 0.f;
    for (int i = t; i < nblk; i += 256) {
        s += part[(size_t)i * 256 + u];
        q += part[(size_t)i * 256 + 128 + u];
    }
    __shared__ float ls[4], lq[4];
    for (int o = 32; o > 0; o >>= 1) {
        s += __shfl_down(s, o, 64);
        q += __shfl_down(q, o, 64);
    }
    int lane = t & 63, w = t >> 6;
    if (lane == 0) { ls[w] = s; lq[w] = q; }
    __syncthreads();
    if (t == 0) {
        float S = ls[0] + ls[1] + ls[2] + ls[3];
        float Q = lq[0] + lq[1] + lq[2] + lq[3];
        float mean = S * invcnt;
        float var = Q * invcnt - mean * mean;
        float inv = rsqrtf(var + BN_EPS);
        float sc = g[u] * inv;
        scale[u] = sc;
        shift[u] = b[u] - mean * sc;
    }
}

// ---------------- edge finalize: wave=2 edges, lane=4 cols; BN apply + s_edge ----------------
__global__ void __launch_bounds__(256) k_edge_final(
        const unsigned short* __restrict__ ebuf, const float* __restrict__ scale,
        const float* __restrict__ shift, const float* __restrict__ aatt,
        float* __restrict__ eout, float* __restrict__ s_edge) {
    int t = threadIdx.x;
    int w = t >> 6, lane = t & 63;
    int q = lane & 31, half = lane >> 5;
    int e = blockIdx.x * 8 + w * 2 + half;

    float4 sc = *reinterpret_cast<const float4*>(scale + q * 4);
    float4 sh = *reinterpret_cast<const float4*>(shift + q * 4);
    float4 a4[8];
#pragma unroll
    for (int h = 0; h < 8; ++h)
        a4[h] = *reinterpret_cast<const float4*>(aatt + h * 384 + 256 + q * 4);

    ushort4 xb = *reinterpret_cast<const ushort4*>(ebuf + (size_t)e * 128 + q * 4);
    float4 x;
    x.x = bf2f(xb.x) * sc.x + sh.x;
    x.y = bf2f(xb.y) * sc.y + sh.y;
    x.z = bf2f(xb.z) * sc.z + sh.z;
    x.w = bf2f(xb.w) * sc.w + sh.w;
    *reinterpret_cast<float4*>(eout + (size_t)e * 128 + q * 4) = x;

    float v[8];
#pragma unroll
    for (int h = 0; h < 8; ++h)
        v[h] = x.x * a4[h].x + x.y * a4[h].y + x.z * a4[h].z + x.w * a4[h].w;
#pragma unroll
    for (int o = 1; o < 32; o <<= 1) {
#pragma unroll
        for (int h = 0; h < 8; ++h) v[h] += __shfl_xor(v[h], o, 64);
    }
    if (q == 0) {
#pragma unroll
        for (int h = 0; h < 8; ++h) s_edge[e * 8 + h] = v[h];
    }
}

// ---------------- attention softmax + aggregation (per dst node, all heads) ----------------
__global__ void k_agg(const unsigned short* __restrict__ zbf, const float* __restrict__ s_src,
                      const float* __restrict__ s_dst, const float* __restrict__ s_edge,
                      const int* __restrict__ off, const int* __restrict__ elist,
                      const int* __restrict__ eidx, float* __restrict__ att) {
    int n = blockIdx.x;
    int t = threadIdx.x;              // 128
    int beg = off[n], end = off[n + 1];
    int deg = end - beg;
    if (deg == 0) { att[(size_t)n * 128 + t] = 0.f; return; }

    float sdh[8];
#pragma unroll
    for (int h = 0; h < 8; ++h) sdh[h] = s_dst[n * 8 + h];

    __shared__ float lred[16];
    __shared__ float wbuf[128][8];
    __shared__ int snbuf[128];

    float mx[8], den[8];
#pragma unroll
    for (int h = 0; h < 8; ++h) { mx[h] = -1e30f; den[h] = 0.f; }

    int lane = t & 63, w = t >> 6;

    // pass 1: running max / denominator (online across chunks of 128)
    for (int c0 = 0; c0 < deg; c0 += 128) {
        int cn = min(128, deg - c0);
        bool act = t < cn;
        int e = 0, sn = 0;
        if (act) { e = elist[beg + c0 + t]; sn = eidx[2 * e + 1]; }
        float lg[8];
#pragma unroll
        for (int h = 0; h < 8; ++h) {
            float x = act ? (s_src[sn * 8 + h] + sdh[h] + s_edge[e * 8 + h]) : -1e30f;
            lg[h] = x >= 0.f ? x : 0.2f * x;
        }
        float cm[8];
#pragma unroll
        for (int h = 0; h < 8; ++h) cm[h] = lg[h];
        for (int o = 32; o > 0; o >>= 1) {
#pragma unroll
            for (int h = 0; h < 8; ++h) cm[h] = fmaxf(cm[h], __shfl_down(cm[h], o, 64));
        }
        if (lane == 0) {
#pragma unroll
            for (int h = 0; h < 8; ++h) lred[w * 8 + h] = cm[h];
        }
        __syncthreads();
#pragma unroll
        for (int h = 0; h < 8; ++h) cm[h] = fmaxf(lred[h], lred[8 + h]);
        __syncthreads();
        float cs[8];
#pragma unroll
        for (int h = 0; h < 8; ++h) cs[h] = act ? __expf(lg[h] - cm[h]) : 0.f;
        for (int o = 32; o > 0; o >>= 1) {
#pragma unroll
            for (int h = 0; h < 8; ++h) cs[h] += __shfl_down(cs[h], o, 64);
        }
        if (lane == 0) {
#pragma unroll
            for (int h = 0; h < 8; ++h) lred[w * 8 + h] = cs[h];
        }
        __syncthreads();
#pragma unroll
        for (int h = 0; h < 8; ++h) {
            float csum = lred[h] + lred[8 + h];
            float nm = fmaxf(mx[h], cm[h]);
            den[h] = den[h] * __expf(mx[h] - nm) + csum * __expf(cm[h] - nm);
            mx[h] = nm;
        }
        __syncthreads();
    }
    float inv[8];
#pragma unroll
    for (int h = 0; h < 8; ++h) inv[h] = 1.f / den[h];

    // pass 2: weights into LDS, then accumulate sum over heads of alpha*z[src]
    float acc = 0.f;
    for (int c0 = 0; c0 < deg; c0 += 128) {
        int cn = min(128, deg - c0);
        if (t < cn) {
            int e = elist[beg + c0 + t];
            int sn = eidx[2 * e + 1];
            snbuf[t] = sn;
#pragma unroll
            for (int h = 0; h < 8; ++h) {
                float x = s_src[sn * 8 + h] + sdh[h] + s_edge[e * 8 + h];
                x = x >= 0.f ? x : 0.2f * x;
                wbuf[t][h] = __expf(x - mx[h]) * inv[h];
            }
        }
        __syncthreads();
        for (int i = 0; i < cn; ++i) {
            int sn = snbuf[i];
            const unsigned short* zr = zbf + (size_t)sn * 1024 + t;
#pragma unroll
            for (int h = 0; h < 8; ++h)
                acc = fmaf(wbuf[i][h], bf2f(zr[h * 128]), acc);
        }
        __syncthreads();
    }
    att[(size_t)n * 128 + t] = fmaxf(acc * 0.125f, 0.f);
}

// ---------------- node MLP: relu(node @ W_node + b), partial BN stats ----------------
__global__ void k_node_mlp(const float* __restrict__ node, const float* __restrict__ Wn,
                           const float* __restrict__ bn, float* __restrict__ nupd,
                           float* __restrict__ part, int N) {
    __shared__ float ash[32][128];
    int n0 = blockIdx.x * 32;
    int t = threadIdx.x;              // 256
    for (int q = t; q < 32 * 128; q += 256) {
        int m = q >> 7, c = q & 127;
        int n = n0 + m;
        ash[m][c] = (n < N) ? node[(size_t)n * 128 + c] : 0.f;
    }
    __syncthreads();
    int u = t & 127, g = t >> 7;
    float acc[16];
    float b = bn[u];
#pragma unroll
    for (int m = 0; m < 16; ++m) acc[m] = b;
    const float* W = Wn + u;
    for (int f = 0; f < 128; f += 4) {
        float w0 = W[(f + 0) * 128], w1 = W[(f + 1) * 128];
        float w2 = W[(f + 2) * 128], w3 = W[(f + 3) * 128];
#pragma unroll
        for (int m = 0; m < 16; ++m) {
            const float4 a = *reinterpret_cast<const float4*>(&ash[g * 16 + m][f]);
            acc[m] = fmaf(a.x, w0, acc[m]);
            acc[m] = fmaf(a.y, w1, acc[m]);
            acc[m] = fmaf(a.z, w2, acc[m]);
            acc[m] = fmaf(a.w, w3, acc[m]);
        }
    }
    float ls = 0.f, lq = 0.f;
#pragma unroll
    for (int m = 0; m < 16; ++m) {
        int n = n0 + g * 16 + m;
        float r = acc[m] > 0.f ? acc[m] : 0.f;
        if (n < N) {
            nupd[(size_t)n * 128 + u] = r;
            ls += r;
            lq += r * r;
        }
    }
    __syncthreads();
    float* red = (float*)ash;
    red[t] = ls;
    red[256 + t] = lq;
    __syncthreads();
    if (g == 0) {
        part[(size_t)blockIdx.x * 256 + u] = red[u] + red[128 + u];
        part[(size_t)blockIdx.x * 256 + 128 + u] = red[256 + u] + red[256 + 128 + u];
    }
}

// ---------------- GRU combine ----------------
__global__ void k_gru(const float* __restrict__ att, const float* __restrict__ nupd,
                      const float* __restrict__ scale, const float* __restrict__ shift,
                      const float* __restrict__ Wk, const float* __restrict__ Wr,
                      const float* __restrict__ gbias, float* __restrict__ outp) {
    __shared__ float ash[16][128];
    __shared__ float ush[16][128];
    __shared__ float zg[16][128];
    __shared__ float rg[16][128];
    int n0 = blockIdx.x * 16;
    int t = threadIdx.x;              // 128
    for (int m = 0; m < 16; ++m) {
        ash[m][t] = att[(size_t)(n0 + m) * 128 + t];
        ush[m][t] = nupd[(size_t)(n0 + m) * 128 + t] * scale[t] + shift[t];
    }
    __syncthreads();
    for (int c = 0; c < 3; ++c) {
        float ax[16], ar[16];
        float bx = gbias[c * 128 + t];
        float br = gbias[384 + c * 128 + t];
#pragma unroll
        for (int m = 0; m < 16; ++m) { ax[m] = bx; ar[m] = br; }
        const float* wkp = Wk + c * 128 + t;
        const float* wrp = Wr + c * 128 + t;
        for (int uu = 0; uu < 128; uu += 4) {
            float wk0 = wkp[(uu + 0) * 384], wk1 = wkp[(uu + 1) * 384];
            float wk2 = wkp[(uu + 2) * 384], wk3 = wkp[(uu + 3) * 384];
            float wr0 = wrp[(uu + 0) * 384], wr1 = wrp[(uu + 1) * 384];
            float wr2 = wrp[(uu + 2) * 384], wr3 = wrp[(uu + 3) * 384];
#pragma unroll
            for (int m = 0; m < 16; ++m) {
                const float4 av = *reinterpret_cast<const float4*>(&ash[m][uu]);
                const float4 uv = *reinterpret_cast<const float4*>(&ush[m][uu]);
                ax[m] = fmaf(av.x, wk0, ax[m]); ax[m] = fmaf(av.y, wk1, ax[m]);
                ax[m] = fmaf(av.z, wk2, ax[m]); ax[m] = fmaf(av.w, wk3, ax[m]);
                ar[m] = fmaf(uv.x, wr0, ar[m]); ar[m] = fmaf(uv.y, wr1, ar[m]);
                ar[m] = fmaf(uv.z, wr2, ar[m]); ar[m] = fmaf(uv.w, wr3, ar[m]);
            }
        }
        if (c == 0) {
#pragma unroll
            for (int m = 0; m < 16; ++m)
                zg[m][t] = 1.f / (1.f + __expf(-(ax[m] + ar[m])));
        } else if (c == 1) {
#pragma unroll
            for (int m = 0; m < 16; ++m)
                rg[m][t] = 1.f / (1.f + __expf(-(ax[m] + ar[m])));
        } else {
#pragma unroll
            for (int m = 0; m < 16; ++m) {
                float hh = tanhf(ax[m] + rg[m][t] * ar[m]);
                float zv = zg[m][t];
                outp[(size_t)(n0 + m) * 128 + t] = zv * ush[m][t] + (1.f - zv) * hh;
            }
        }
    }
}

// ---------------- launch ----------------
extern "C" void kernel_launch(void* const* d_in, const int* in_sizes, int n_in,
                              void* d_out, int out_size, void* d_ws, size_t ws_size,
                              hipStream_t stream) {
    const float* node    = (const float*)d_in[0];
    const float* eattr   = (const float*)d_in[1];
    const int*   eidx    = (const int*)d_in[2];
    const float* We      = (const float*)d_in[3];
    const float* be      = (const float*)d_in[4];
    const float* gamma_e = (const float*)d_in[5];
    const float* beta_e  = (const float*)d_in[6];
    const float* Wn      = (const float*)d_in[7];
    const float* bnb     = (const float*)d_in[8];
    const float* gamma_n = (const float*)d_in[9];
    const float* beta_n  = (const float*)d_in[10];
    const float* Watt    = (const float*)d_in[11];
    const float* batt    = (const float*)d_in[12];
    const float* aatt    = (const float*)d_in[13];
    const float* Wk      = (const float*)d_in[14];
    const float* Wr      = (const float*)d_in[15];
    const float* gbias   = (const float*)d_in[16];

    float* out_node = (float*)d_out;
    float* out_edge = out_node + (size_t)NN * UU;

    char* wp = (char*)d_ws;
    auto alloc = [&](size_t bytes) {
        void* p = (void*)wp;
        wp += (bytes + 255) / 256 * 256;
        return p;
    };
    // zbf (bf16, 20.5MB) shares a region with eattr_bf (bf16, 41MB); eattr_bf dead before k_z_mfma
    unsigned short* zregion = (unsigned short*)alloc((size_t)EE * 128 * 2);
    unsigned short* zbf      = zregion;
    unsigned short* eattr_bf = zregion;
    unsigned short* ebuf = (unsigned short*)alloc((size_t)EE * 128 * 2);
    float* s_src   = (float*)alloc((size_t)NN * 8 * 4);
    float* s_dst   = (float*)alloc((size_t)NN * 8 * 4);
    float* s_edge  = (float*)alloc((size_t)EE * 8 * 4);
    float* part_e  = (float*)alloc((size_t)2500 * 256 * 4);
    float* part_n  = (float*)alloc((size_t)313 * 256 * 4);
    float* scale_e = (float*)alloc(512);
    float* shift_e = (float*)alloc(512);
    float* scale_n = (float*)alloc(512);
    float* shift_n = (float*)alloc(512);
    float* attend  = (float*)alloc((size_t)NN * 128 * 4);
    float* nupd    = (float*)alloc((size_t)NN * 128 * 4);
    int*   cnt     = (int*)alloc((size_t)NN * 4);
    int*   offs    = (int*)alloc((size_t)(NN + 1) * 4);
    int*   cursor  = (int*)alloc((size_t)NN * 4);
    int*   elist   = (int*)alloc((size_t)EE * 4);
    unsigned short* node_bf = (unsigned short*)alloc((size_t)NN * 128 * 2);
    unsigned short* Wt      = (unsigned short*)alloc((size_t)128 * 384 * 2);
    unsigned short* WtA     = (unsigned short*)alloc((size_t)8 * 128 * 128 * 2);

    hipMemsetAsync(cnt, 0, (size_t)NN * 4, stream);
    k_hist<<<(EE + 255) / 256, 256, 0, stream>>>(eidx, cnt, EE);
    k_scan<<<1, 1024, 0, stream>>>(cnt, offs, cursor, NN);
    k_scatter<<<(EE + 255) / 256, 256, 0, stream>>>(eidx, cursor, elist, EE);

    // bf16 conversions
    k_f2bf<<<1280, 256, 0, stream>>>(node, node_bf, (long)NN * 128 / 4);
    k_f2bf<<<2048, 256, 0, stream>>>(eattr, eattr_bf, (long)EE * 128 / 4);
    k_wt<<<(384 * 128 + 255) / 256, 256, 0, stream>>>(We, Wt);
    k_wt_att<<<(8 * 128 * 128 + 255) / 256, 256, 0, stream>>>(Watt, WtA);

    // edge pipeline (uses eattr_bf which aliases zbf; must precede k_z_mfma)
    k_edge_mlp_mfma<<<EE / 64, 256, 0, stream>>>(node_bf, eattr_bf, eidx, Wt, be, ebuf, part_e);
    k_bn_fin<<<128, 256, 0, stream>>>(part_e, EE / 64, 1.f / (float)EE,
                                      gamma_e, beta_e, scale_e, shift_e);
    k_edge_final<<<EE / 8, 256, 0, stream>>>(ebuf, scale_e, shift_e, aatt, out_edge, s_edge);

    // node/attention pipeline
    k_z_mfma<<<dim3((NN + 63) / 64, 8), 256, 0, stream>>>(node_bf, WtA, batt, zbf, NN);
    k_snodes<<<NN / 4, 256, 0, stream>>>(zbf, aatt, s_src, s_dst, NN);
    k_agg<<<NN, 128, 0, stream>>>(zbf, s_src, s_dst, s_edge, offs, elist, eidx, attend);

    k_node_mlp<<<(NN + 31) / 32, 256, 0, stream>>>(node, Wn, bnb, nupd, part_n, NN);
    k_bn_fin<<<128, 256, 0, stream>>>(part_n, (NN + 31) / 32, 1.f / (float)NN,
                                      gamma_n, beta_n, scale_n, shift_n);
    k_gru<<<NN / 16, 128, 0, stream>>>(attend, nupd, scale_n, shift_n, Wk, Wr, gbias, out_node);
}

// Round 5
// 352.355 us; speedup vs baseline: 3.1829x; 1.2188x over previous
//
#include <hip/hip_runtime.h>
#include <hip/hip_bf16.h>

#define NN 10000
#define EE 160000
#define FF 128
#define UU 128
#define HH 8
#define BN_EPS 1e-3f

typedef __attribute__((ext_vector_type(8))) short bf16x8;
typedef __attribute__((ext_vector_type(8))) unsigned short u16x8;
typedef __attribute__((ext_vector_type(4))) float f32x4;

static __device__ __forceinline__ unsigned short f2bf(float f) {
    unsigned u = __float_as_uint(f);
    u += 0x7fffu + ((u >> 16) & 1u);
    return (unsigned short)(u >> 16);
}
static __device__ __forceinline__ float bf2f(unsigned short b) {
    return __uint_as_float((unsigned)b << 16);
}

// ---------------- f32 -> bf16 bulk convert (count divisible by 4) ----------------
__global__ void k_f2bf(const float* __restrict__ in, unsigned short* __restrict__ out, long n4) {
    long i = (long)blockIdx.x * 256 + threadIdx.x;
    long stride = (long)gridDim.x * 256;
    for (; i < n4; i += stride) {
        float4 v = reinterpret_cast<const float4*>(in)[i];
        ushort4 o;
        o.x = f2bf(v.x); o.y = f2bf(v.y); o.z = f2bf(v.z); o.w = f2bf(v.w);
        reinterpret_cast<ushort4*>(out)[i] = o;
    }
}

// ---------------- generic W [K][U] f32 -> W^T [U][K] bf16 ----------------
__global__ void k_wtg(const float* __restrict__ W, unsigned short* __restrict__ Wt, int K, int U) {
    int i = blockIdx.x * 256 + threadIdx.x;
    if (i < K * U) {
        int k = i / U, u = i - k * U;
        Wt[u * K + k] = f2bf(W[i]);
    }
}

// ---------------- W_att [8][128][128] f32 -> per-head W^T [8][128][128] bf16 ----------------
__global__ void k_wt_att(const float* __restrict__ W, unsigned short* __restrict__ Wt) {
    int i = blockIdx.x * 256 + threadIdx.x;   // over 8*128*128
    if (i < 8 * 128 * 128) {
        int h = i >> 14, rem = i & 16383, f = rem >> 7, u = rem & 127;
        Wt[h * 16384 + u * 128 + f] = f2bf(W[i]);
    }
}

// ---------------- GRU combined weight: WcT [512][256] bf16 ----------------
// S = [att | ush] @ Wc.  cols 0-255: z,r gates (Wk ; Wr summed via concat-K),
// cols 256-383: Wk_h (zeros for k>=128), cols 384-511: Wr_h (zeros for k<128).
__global__ void k_wt_gru(const float* __restrict__ Wk, const float* __restrict__ Wr,
                         unsigned short* __restrict__ WcT) {
    int i = blockIdx.x * 256 + threadIdx.x;   // over 512*256
    if (i >= 512 * 256) return;
    int c = i >> 8, k = i & 255;
    float v;
    if (c < 256)       v = (k < 128) ? Wk[k * 384 + c] : Wr[(k - 128) * 384 + c];
    else if (c < 384)  v = (k < 128) ? Wk[k * 384 + c] : 0.f;
    else               v = (k < 128) ? 0.f : Wr[(k - 128) * 384 + (c - 128)];
    WcT[c * 256 + k] = f2bf(v);
}

// ---------------- CSR construction ----------------
__global__ void k_hist(const int* __restrict__ eidx, int* __restrict__ cnt, int E) {
    int e = blockIdx.x * 256 + threadIdx.x;
    if (e < E) atomicAdd(&cnt[eidx[2 * e]], 1);   // dst = eidx[e][0]
}

__global__ void k_scan(const int* __restrict__ cnt, int* __restrict__ off,
                       int* __restrict__ cursor, int N) {
    __shared__ int s[1024];
    int t = threadIdx.x;
    int run = 0;
    if (t == 0) off[0] = 0;
    for (int base = 0; base < N; base += 1024) {
        int x = (base + t < N) ? cnt[base + t] : 0;
        s[t] = x;
        __syncthreads();
        for (int o = 1; o < 1024; o <<= 1) {
            int v = (t >= o) ? s[t - o] : 0;
            __syncthreads();
            s[t] += v;
            __syncthreads();
        }
        if (base + t < N) {
            off[base + t + 1] = run + s[t];
            cursor[base + t] = run + s[t] - x;
        }
        run += s[1023];
        __syncthreads();
    }
}

__global__ void k_scatter(const int* __restrict__ eidx, int* __restrict__ cursor,
                          int* __restrict__ elist, int E) {
    int e = blockIdx.x * 256 + threadIdx.x;
    if (e < E) {
        int d = eidx[2 * e];
        int p = atomicAdd(&cursor[d], 1);
        elist[p] = e;
    }
}

// ---------------- z (bf16) = node @ W_att[h] + b_att[h], MFMA, stored (N,H,U) ----------------
__global__ void __launch_bounds__(256) k_z_mfma(
        const unsigned short* __restrict__ node_bf, const unsigned short* __restrict__ WtA,
        const float* __restrict__ batt, unsigned short* __restrict__ zbf, int N) {
    __shared__ unsigned short ash[64][136];     // 128 + 8 pad
    int n0 = blockIdx.x * 64;
    int h = blockIdx.y;
    int t = threadIdx.x;
    for (int q = t; q < 64 * 16; q += 256) {
        int r = q >> 4, c = q & 15;
        int n = n0 + r; if (n >= N) n = N - 1;
        *reinterpret_cast<uint4*>(&ash[r][c * 8]) =
            *reinterpret_cast<const uint4*>(node_bf + (size_t)n * 128 + c * 8);
    }
    __syncthreads();

    int wid = t >> 6, lane = t & 63;
    int wm = wid >> 1, wn = wid & 1;
    int lr = lane & 15, lg = lane >> 4;

    f32x4 acc[2][4];
#pragma unroll
    for (int m = 0; m < 2; ++m)
#pragma unroll
        for (int n = 0; n < 4; ++n) acc[m][n] = (f32x4){0.f, 0.f, 0.f, 0.f};

    const unsigned short* Wh = WtA + (size_t)h * 16384;
#pragma unroll
    for (int ks = 0; ks < 4; ++ks) {
        int kb = ks * 32 + lg * 8;
        bf16x8 a0 = *reinterpret_cast<const bf16x8*>(&ash[wm * 32 + lr][kb]);
        bf16x8 a1 = *reinterpret_cast<const bf16x8*>(&ash[wm * 32 + 16 + lr][kb]);
        bf16x8 b[4];
#pragma unroll
        for (int n = 0; n < 4; ++n)
            b[n] = *reinterpret_cast<const bf16x8*>(Wh + (size_t)(wn * 64 + n * 16 + lr) * 128 + kb);
#pragma unroll
        for (int n = 0; n < 4; ++n) {
            acc[0][n] = __builtin_amdgcn_mfma_f32_16x16x32_bf16(a0, b[n], acc[0][n], 0, 0, 0);
            acc[1][n] = __builtin_amdgcn_mfma_f32_16x16x32_bf16(a1, b[n], acc[1][n], 0, 0, 0);
        }
    }

#pragma unroll
    for (int n = 0; n < 4; ++n) {
        int col = wn * 64 + n * 16 + lr;
        float bias = batt[h * 128 + col];
#pragma unroll
        for (int m = 0; m < 2; ++m) {
            int rowb = wm * 32 + m * 16 + lg * 4;
#pragma unroll
            for (int r = 0; r < 4; ++r) {
                int row = n0 + rowb + r;
                if (row < N)
                    zbf[(size_t)row * 1024 + h * 128 + col] = f2bf(acc[m][n][r] + bias);
            }
        }
    }
}

// ---------------- s_src[n,h], s_dst[n,h]: wave=node, lane=(head, 16-col slice) ----------------
__global__ void __launch_bounds__(256) k_snodes(
        const unsigned short* __restrict__ zbf, const float* __restrict__ aatt,
        float* __restrict__ s_src, float* __restrict__ s_dst, int N) {
    int t = threadIdx.x;
    int w = t >> 6, lane = t & 63;
    int n = blockIdx.x * 4 + w;
    if (n >= N) return;
    int h = lane >> 3, p = lane & 7;
    const unsigned short* zp = zbf + (size_t)n * 1024 + h * 128 + p * 16;
    const float* as = aatt + h * 384 + p * 16;
    u16x8 z0 = *reinterpret_cast<const u16x8*>(zp);
    u16x8 z1 = *reinterpret_cast<const u16x8*>(zp + 8);
    float vs = 0.f, vd = 0.f;
#pragma unroll
    for (int j = 0; j < 8; ++j) {
        float zv = bf2f(z0[j]);
        vs = fmaf(zv, as[j], vs);
        vd = fmaf(zv, as[128 + j], vd);
    }
#pragma unroll
    for (int j = 0; j < 8; ++j) {
        float zv = bf2f(z1[j]);
        vs = fmaf(zv, as[8 + j], vs);
        vd = fmaf(zv, as[136 + j], vd);
    }
#pragma unroll
    for (int o = 1; o < 8; o <<= 1) {
        vs += __shfl_xor(vs, o, 64);
        vd += __shfl_xor(vd, o, 64);
    }
    if (p == 0) {
        s_src[n * 8 + h] = vs;
        s_dst[n * 8 + h] = vd;
    }
}

// ---------------- edge MLP via MFMA bf16: relu(concat @ W_edge + b), BN partials ----------------
__global__ void __launch_bounds__(256) k_edge_mlp_mfma(
        const unsigned short* __restrict__ node_bf, const unsigned short* __restrict__ eattr_bf,
        const int* __restrict__ eidx, const unsigned short* __restrict__ Wt,
        const float* __restrict__ be, unsigned short* __restrict__ ebuf, float* __restrict__ part) {
    __shared__ unsigned short ash[64][392];     // 384 + 8 pad
    __shared__ int sd[128];
    __shared__ float sbuf[4][64], qbuf[4][64];
    int e0 = blockIdx.x * 64;
    int t = threadIdx.x;
    if (t < 128) sd[t] = eidx[e0 * 2 + t];      // [e][0]=dst, [e][1]=src
    __syncthreads();
    for (int q = t; q < 64 * 48; q += 256) {
        int r = q / 48, c = q - r * 48;
        const unsigned short* sp;
        if (c < 16)      sp = node_bf + (size_t)sd[r * 2 + 1] * 128 + c * 8;
        else if (c < 32) sp = node_bf + (size_t)sd[r * 2] * 128 + (c - 16) * 8;
        else             sp = eattr_bf + (size_t)(e0 + r) * 128 + (c - 32) * 8;
        *reinterpret_cast<uint4*>(&ash[r][c * 8]) = *reinterpret_cast<const uint4*>(sp);
    }
    __syncthreads();

    int wid = t >> 6, lane = t & 63;
    int wm = wid >> 1, wn = wid & 1;
    int lr = lane & 15, lg = lane >> 4;

    f32x4 acc[2][4];
#pragma unroll
    for (int m = 0; m < 2; ++m)
#pragma unroll
        for (int n = 0; n < 4; ++n) acc[m][n] = (f32x4){0.f, 0.f, 0.f, 0.f};

#pragma unroll
    for (int ks = 0; ks < 12; ++ks) {
        int kb = ks * 32 + lg * 8;
        bf16x8 a0 = *reinterpret_cast<const bf16x8*>(&ash[wm * 32 + lr][kb]);
        bf16x8 a1 = *reinterpret_cast<const bf16x8*>(&ash[wm * 32 + 16 + lr][kb]);
        bf16x8 b[4];
#pragma unroll
        for (int n = 0; n < 4; ++n)
            b[n] = *reinterpret_cast<const bf16x8*>(Wt + (size_t)(wn * 64 + n * 16 + lr) * 384 + kb);
#pragma unroll
        for (int n = 0; n < 4; ++n) {
            acc[0][n] = __builtin_amdgcn_mfma_f32_16x16x32_bf16(a0, b[n], acc[0][n], 0, 0, 0);
            acc[1][n] = __builtin_amdgcn_mfma_f32_16x16x32_bf16(a1, b[n], acc[1][n], 0, 0, 0);
        }
    }

    float s[4] = {0.f, 0.f, 0.f, 0.f}, q[4] = {0.f, 0.f, 0.f, 0.f};
#pragma unroll
    for (int n = 0; n < 4; ++n) {
        int col = wn * 64 + n * 16 + lr;
        float bias = be[col];
#pragma unroll
        for (int m = 0; m < 2; ++m) {
            int rowb = wm * 32 + m * 16 + lg * 4;
#pragma unroll
            for (int r = 0; r < 4; ++r) {
                float v = acc[m][n][r] + bias;
                v = v > 0.f ? v : 0.f;
                ebuf[(size_t)(e0 + rowb + r) * 128 + col] = f2bf(v);
                s[n] += v;
                q[n] += v * v;
            }
        }
    }
#pragma unroll
    for (int n = 0; n < 4; ++n) {
        s[n] += __shfl_xor(s[n], 16, 64);
        s[n] += __shfl_xor(s[n], 32, 64);
        q[n] += __shfl_xor(q[n], 16, 64);
        q[n] += __shfl_xor(q[n], 32, 64);
    }
    if (lane < 16) {
#pragma unroll
        for (int n = 0; n < 4; ++n) {
            sbuf[wid][n * 16 + lane] = s[n];
            qbuf[wid][n * 16 + lane] = q[n];
        }
    }
    __syncthreads();
    if (t < 128) {
        int half = t >> 6, c = t & 63;
        part[(size_t)blockIdx.x * 256 + t] = sbuf[half][c] + sbuf[2 + half][c];
        part[(size_t)blockIdx.x * 256 + 128 + t] = qbuf[half][c] + qbuf[2 + half][c];
    }
}

// ---------------- node MLP via MFMA: relu(node @ W_node + b), BN partials ----------------
__global__ void __launch_bounds__(256) k_node_mlp_mfma(
        const unsigned short* __restrict__ node_bf, const unsigned short* __restrict__ WnT,
        const float* __restrict__ bn, float* __restrict__ nupd, float* __restrict__ part, int N) {
    __shared__ unsigned short ash[64][136];
    __shared__ float sbuf[4][64], qbuf[4][64];
    int n0 = blockIdx.x * 64;
    int t = threadIdx.x;
    for (int q = t; q < 64 * 16; q += 256) {
        int r = q >> 4, c = q & 15;
        int n = n0 + r; if (n >= N) n = N - 1;
        *reinterpret_cast<uint4*>(&ash[r][c * 8]) =
            *reinterpret_cast<const uint4*>(node_bf + (size_t)n * 128 + c * 8);
    }
    __syncthreads();

    int wid = t >> 6, lane = t & 63;
    int wm = wid >> 1, wn = wid & 1;
    int lr = lane & 15, lg = lane >> 4;

    f32x4 acc[2][4];
#pragma unroll
    for (int m = 0; m < 2; ++m)
#pragma unroll
        for (int n = 0; n < 4; ++n) acc[m][n] = (f32x4){0.f, 0.f, 0.f, 0.f};

#pragma unroll
    for (int ks = 0; ks < 4; ++ks) {
        int kb = ks * 32 + lg * 8;
        bf16x8 a0 = *reinterpret_cast<const bf16x8*>(&ash[wm * 32 + lr][kb]);
        bf16x8 a1 = *reinterpret_cast<const bf16x8*>(&ash[wm * 32 + 16 + lr][kb]);
        bf16x8 b[4];
#pragma unroll
        for (int n = 0; n < 4; ++n)
            b[n] = *reinterpret_cast<const bf16x8*>(WnT + (size_t)(wn * 64 + n * 16 + lr) * 128 + kb);
#pragma unroll
        for (int n = 0; n < 4; ++n) {
            acc[0][n] = __builtin_amdgcn_mfma_f32_16x16x32_bf16(a0, b[n], acc[0][n], 0, 0, 0);
            acc[1][n] = __builtin_amdgcn_mfma_f32_16x16x32_bf16(a1, b[n], acc[1][n], 0, 0, 0);
        }
    }

    float s[4] = {0.f, 0.f, 0.f, 0.f}, q[4] = {0.f, 0.f, 0.f, 0.f};
#pragma unroll
    for (int n = 0; n < 4; ++n) {
        int col = wn * 64 + n * 16 + lr;
        float bias = bn[col];
#pragma unroll
        for (int m = 0; m < 2; ++m) {
            int rowb = wm * 32 + m * 16 + lg * 4;
#pragma unroll
            for (int r = 0; r < 4; ++r) {
                int row = n0 + rowb + r;
                float v = acc[m][n][r] + bias;
                v = v > 0.f ? v : 0.f;
                if (row < N) {
                    nupd[(size_t)row * 128 + col] = v;
                    s[n] += v;
                    q[n] += v * v;
                }
            }
        }
    }
#pragma unroll
    for (int n = 0; n < 4; ++n) {
        s[n] += __shfl_xor(s[n], 16, 64);
        s[n] += __shfl_xor(s[n], 32, 64);
        q[n] += __shfl_xor(q[n], 16, 64);
        q[n] += __shfl_xor(q[n], 32, 64);
    }
    if (lane < 16) {
#pragma unroll
        for (int n = 0; n < 4; ++n) {
            sbuf[wid][n * 16 + lane] = s[n];
            qbuf[wid][n * 16 + lane] = q[n];
        }
    }
    __syncthreads();
    if (t < 128) {
        int half = t >> 6, c = t & 63;
        part[(size_t)blockIdx.x * 256 + t] = sbuf[half][c] + sbuf[2 + half][c];
        part[(size_t)blockIdx.x * 256 + 128 + t] = qbuf[half][c] + qbuf[2 + half][c];
    }
}

// ---------------- BN finalize: scale/shift per column ----------------
__global__ void k_bn_fin(const float* __restrict__ part, int nblk, float invcnt,
                         const float* __restrict__ g, const float* __restrict__ b,
                         float* __restrict__ scale, float* __restrict__ shift) {
    int u = blockIdx.x;               // 128 blocks
    int t = threadIdx.x;              // 256
    float s = 0.f, q = 0.f;
    for (int i = t; i < nblk; i += 256) {
        s += part[(size_t)i * 256 + u];
        q += part[(size_t)i * 256 + 128 + u];
    }
    __shared__ float ls[4], lq[4];
    for (int o = 32; o > 0; o >>= 1) {
        s += __shfl_down(s, o, 64);
        q += __shfl_down(q, o, 64);
    }
    int lane = t & 63, w = t >> 6;
    if (lane == 0) { ls[w] = s; lq[w] = q; }
    __syncthreads();
    if (t == 0) {
        float S = ls[0] + ls[1] + ls[2] + ls[3];
        float Q = lq[0] + lq[1] + lq[2] + lq[3];
        float mean = S * invcnt;
        float var = Q * invcnt - mean * mean;
        float inv = rsqrtf(var + BN_EPS);
        float sc = g[u] * inv;
        scale[u] = sc;
        shift[u] = b[u] - mean * sc;
    }
}

// ---------------- edge finalize: wave=2 edges, lane=4 cols; BN apply + s_edge ----------------
__global__ void __launch_bounds__(256) k_edge_final(
        const unsigned short* __restrict__ ebuf, const float* __restrict__ scale,
        const float* __restrict__ shift, const float* __restrict__ aatt,
        float* __restrict__ eout, float* __restrict__ s_edge) {
    int t = threadIdx.x;
    int w = t >> 6, lane = t & 63;
    int q = lane & 31, half = lane >> 5;
    int e = blockIdx.x * 8 + w * 2 + half;

    float4 sc = *reinterpret_cast<const float4*>(scale + q * 4);
    float4 sh = *reinterpret_cast<const float4*>(shift + q * 4);
    float4 a4[8];
#pragma unroll
    for (int h = 0; h < 8; ++h)
        a4[h] = *reinterpret_cast<const float4*>(aatt + h * 384 + 256 + q * 4);

    ushort4 xb = *reinterpret_cast<const ushort4*>(ebuf + (size_t)e * 128 + q * 4);
    float4 x;
    x.x = bf2f(xb.x) * sc.x + sh.x;
    x.y = bf2f(xb.y) * sc.y + sh.y;
    x.z = bf2f(xb.z) * sc.z + sh.z;
    x.w = bf2f(xb.w) * sc.w + sh.w;
    *reinterpret_cast<float4*>(eout + (size_t)e * 128 + q * 4) = x;

    float v[8];
#pragma unroll
    for (int h = 0; h < 8; ++h)
        v[h] = x.x * a4[h].x + x.y * a4[h].y + x.z * a4[h].z + x.w * a4[h].w;
#pragma unroll
    for (int o = 1; o < 32; o <<= 1) {
#pragma unroll
        for (int h = 0; h < 8; ++h) v[h] += __shfl_xor(v[h], o, 64);
    }
    if (q == 0) {
#pragma unroll
        for (int h = 0; h < 8; ++h) s_edge[e * 8 + h] = v[h];
    }
}

// ---------------- attention softmax + aggregation; writes bf16 into cat[:,0:128] ----------------
__global__ void k_agg(const unsigned short* __restrict__ zbf, const float* __restrict__ s_src,
                      const float* __restrict__ s_dst, const float* __restrict__ s_edge,
                      const int* __restrict__ off, const int* __restrict__ elist,
                      const int* __restrict__ eidx, unsigned short* __restrict__ cat) {
    int n = blockIdx.x;
    int t = threadIdx.x;              // 128
    int beg = off[n], end = off[n + 1];
    int deg = end - beg;
    if (deg == 0) { cat[(size_t)n * 256 + t] = 0; return; }

    float sdh[8];
#pragma unroll
    for (int h = 0; h < 8; ++h) sdh[h] = s_dst[n * 8 + h];

    __shared__ float lred[16];
    __shared__ float wbuf[128][8];
    __shared__ int snbuf[128];

    float mx[8], den[8];
#pragma unroll
    for (int h = 0; h < 8; ++h) { mx[h] = -1e30f; den[h] = 0.f; }

    int lane = t & 63, w = t >> 6;

    // pass 1: running max / denominator (online across chunks of 128)
    for (int c0 = 0; c0 < deg; c0 += 128) {
        int cn = min(128, deg - c0);
        bool act = t < cn;
        int e = 0, sn = 0;
        if (act) { e = elist[beg + c0 + t]; sn = eidx[2 * e + 1]; }
        float lg[8];
#pragma unroll
        for (int h = 0; h < 8; ++h) {
            float x = act ? (s_src[sn * 8 + h] + sdh[h] + s_edge[e * 8 + h]) : -1e30f;
            lg[h] = x >= 0.f ? x : 0.2f * x;
        }
        float cm[8];
#pragma unroll
        for (int h = 0; h < 8; ++h) cm[h] = lg[h];
        for (int o = 32; o > 0; o >>= 1) {
#pragma unroll
            for (int h = 0; h < 8; ++h) cm[h] = fmaxf(cm[h], __shfl_down(cm[h], o, 64));
        }
        if (lane == 0) {
#pragma unroll
            for (int h = 0; h < 8; ++h) lred[w * 8 + h] = cm[h];
        }
        __syncthreads();
#pragma unroll
        for (int h = 0; h < 8; ++h) cm[h] = fmaxf(lred[h], lred[8 + h]);
        __syncthreads();
        float cs[8];
#pragma unroll
        for (int h = 0; h < 8; ++h) cs[h] = act ? __expf(lg[h] - cm[h]) : 0.f;
        for (int o = 32; o > 0; o >>= 1) {
#pragma unroll
            for (int h = 0; h < 8; ++h) cs[h] += __shfl_down(cs[h], o, 64);
        }
        if (lane == 0) {
#pragma unroll
            for (int h = 0; h < 8; ++h) lred[w * 8 + h] = cs[h];
        }
        __syncthreads();
#pragma unroll
        for (int h = 0; h < 8; ++h) {
            float csum = lred[h] + lred[8 + h];
            float nm = fmaxf(mx[h], cm[h]);
            den[h] = den[h] * __expf(mx[h] - nm) + csum * __expf(cm[h] - nm);
            mx[h] = nm;
        }
        __syncthreads();
    }
    float inv[8];
#pragma unroll
    for (int h = 0; h < 8; ++h) inv[h] = 1.f / den[h];

    // pass 2: weights into LDS, then accumulate sum over heads of alpha*z[src]
    float acc = 0.f;
    for (int c0 = 0; c0 < deg; c0 += 128) {
        int cn = min(128, deg - c0);
        if (t < cn) {
            int e = elist[beg + c0 + t];
            int sn = eidx[2 * e + 1];
            snbuf[t] = sn;
#pragma unroll
            for (int h = 0; h < 8; ++h) {
                float x = s_src[sn * 8 + h] + sdh[h] + s_edge[e * 8 + h];
                x = x >= 0.f ? x : 0.2f * x;
                wbuf[t][h] = __expf(x - mx[h]) * inv[h];
            }
        }
        __syncthreads();
        for (int i = 0; i < cn; ++i) {
            int sn = snbuf[i];
            const unsigned short* zr = zbf + (size_t)sn * 1024 + t;
#pragma unroll
            for (int h = 0; h < 8; ++h)
                acc = fmaf(wbuf[i][h], bf2f(zr[h * 128]), acc);
        }
        __syncthreads();
    }
    cat[(size_t)n * 256 + t] = f2bf(fmaxf(acc * 0.125f, 0.f));
}

// ---------------- GRU pre: ush = BN(nupd); cat[:,128:256] = bf16(ush) ----------------
__global__ void k_gru_pre(const float* __restrict__ nupd, const float* __restrict__ scale,
                          const float* __restrict__ shift, unsigned short* __restrict__ cat,
                          float* __restrict__ ush) {
    int i = blockIdx.x * 256 + threadIdx.x;   // over NN*32
    if (i >= NN * 32) return;
    int n = i >> 5, j4 = (i & 31) * 4;
    float4 u = *reinterpret_cast<const float4*>(nupd + (size_t)n * 128 + j4);
    float4 sc = *reinterpret_cast<const float4*>(scale + j4);
    float4 sh = *reinterpret_cast<const float4*>(shift + j4);
    float4 uv;
    uv.x = u.x * sc.x + sh.x;
    uv.y = u.y * sc.y + sh.y;
    uv.z = u.z * sc.z + sh.z;
    uv.w = u.w * sc.w + sh.w;
    ushort4 ub;
    ub.x = f2bf(uv.x); ub.y = f2bf(uv.y); ub.z = f2bf(uv.z); ub.w = f2bf(uv.w);
    *reinterpret_cast<ushort4*>(cat + (size_t)n * 256 + 128 + j4) = ub;
    *reinterpret_cast<float4*>(ush + (size_t)n * 128 + j4) = uv;
}

// ---------------- GRU GEMM: S = cat @ Wc  (M x 256 x 512), MFMA ----------------
__global__ void __launch_bounds__(256) k_gru_mm(
        const unsigned short* __restrict__ cat, const unsigned short* __restrict__ WcT,
        float* __restrict__ S, int N) {
    __shared__ unsigned short ash[64][264];     // 256 + 8 pad
    int n0 = blockIdx.x * 64;
    int g = blockIdx.y;                          // col group 0..3
    int t = threadIdx.x;
    for (int q = t; q < 64 * 32; q += 256) {
        int r = q >> 5, c = q & 31;
        int n = n0 + r; if (n >= N) n = N - 1;
        *reinterpret_cast<uint4*>(&ash[r][c * 8]) =
            *reinterpret_cast<const uint4*>(cat + (size_t)n * 256 + c * 8);
    }
    __syncthreads();

    int wid = t >> 6, lane = t & 63;
    int wm = wid >> 1, wn = wid & 1;
    int lr = lane & 15, lg = lane >> 4;

    f32x4 acc[2][4];
#pragma unroll
    for (int m = 0; m < 2; ++m)
#pragma unroll
        for (int n = 0; n < 4; ++n) acc[m][n] = (f32x4){0.f, 0.f, 0.f, 0.f};

    const unsigned short* Wg = WcT + (size_t)g * 128 * 256;
#pragma unroll
    for (int ks = 0; ks < 8; ++ks) {
        int kb = ks * 32 + lg * 8;
        bf16x8 a0 = *reinterpret_cast<const bf16x8*>(&ash[wm * 32 + lr][kb]);
        bf16x8 a1 = *reinterpret_cast<const bf16x8*>(&ash[wm * 32 + 16 + lr][kb]);
        bf16x8 b[4];
#pragma unroll
        for (int n = 0; n < 4; ++n)
            b[n] = *reinterpret_cast<const bf16x8*>(Wg + (size_t)(wn * 64 + n * 16 + lr) * 256 + kb);
#pragma unroll
        for (int n = 0; n < 4; ++n) {
            acc[0][n] = __builtin_amdgcn_mfma_f32_16x16x32_bf16(a0, b[n], acc[0][n], 0, 0, 0);
            acc[1][n] = __builtin_amdgcn_mfma_f32_16x16x32_bf16(a1, b[n], acc[1][n], 0, 0, 0);
        }
    }

#pragma unroll
    for (int n = 0; n < 4; ++n) {
        int col = g * 128 + wn * 64 + n * 16 + lr;
#pragma unroll
        for (int m = 0; m < 2; ++m) {
            int rowb = wm * 32 + m * 16 + lg * 4;
#pragma unroll
            for (int r = 0; r < 4; ++r) {
                int row = n0 + rowb + r;
                if (row < N) S[(size_t)row * 512 + col] = acc[m][n][r];
            }
        }
    }
}

// ---------------- GRU gates: sigmoid/tanh + combine ----------------
__global__ void __launch_bounds__(256) k_gru_gates(
        const float* __restrict__ S, const float* __restrict__ ush,
        const float* __restrict__ gbias, float* __restrict__ outp) {
    int t = threadIdx.x;
    int n = blockIdx.x * 2 + (t >> 7);
    int u = t & 127;
    const float* b0 = gbias;
    const float* b1 = gbias + 384;
    float s0 = S[(size_t)n * 512 + u];
    float s1 = S[(size_t)n * 512 + 128 + u];
    float xh = S[(size_t)n * 512 + 256 + u];
    float rh = S[(size_t)n * 512 + 384 + u];
    float zg = 1.f / (1.f + __expf(-(s0 + b0[u] + b1[u])));
    float rg = 1.f / (1.f + __expf(-(s1 + b0[128 + u] + b1[128 + u])));
    float hh = tanhf(xh + b0[256 + u] + rg * (rh + b1[256 + u]));
    float uv = ush[(size_t)n * 128 + u];
    outp[(size_t)n * 128 + u] = zg * uv + (1.f - zg) * hh;
}

// ---------------- launch ----------------
extern "C" void kernel_launch(void* const* d_in, const int* in_sizes, int n_in,
                              void* d_out, int out_size, void* d_ws, size_t ws_size,
                              hipStream_t stream) {
    const float* node    = (const float*)d_in[0];
    const float* eattr   = (const float*)d_in[1];
    const int*   eidx    = (const int*)d_in[2];
    const float* We      = (const float*)d_in[3];
    const float* be      = (const float*)d_in[4];
    const float* gamma_e = (const float*)d_in[5];
    const float* beta_e  = (const float*)d_in[6];
    const float* Wn      = (const float*)d_in[7];
    const float* bnb     = (const float*)d_in[8];
    const float* gamma_n = (const float*)d_in[9];
    const float* beta_n  = (const float*)d_in[10];
    const float* Watt    = (const float*)d_in[11];
    const float* batt    = (const float*)d_in[12];
    const float* aatt    = (const float*)d_in[13];
    const float* Wk      = (const float*)d_in[14];
    const float* Wr      = (const float*)d_in[15];
    const float* gbias   = (const float*)d_in[16];

    float* out_node = (float*)d_out;
    float* out_edge = out_node + (size_t)NN * UU;

    char* wp = (char*)d_ws;
    auto alloc = [&](size_t bytes) {
        void* p = (void*)wp;
        wp += (bytes + 255) / 256 * 256;
        return p;
    };
    // zbf (bf16, 20.5MB) shares a region with eattr_bf (bf16, 41MB); eattr_bf dead before k_z_mfma
    unsigned short* zregion = (unsigned short*)alloc((size_t)EE * 128 * 2);
    unsigned short* zbf      = zregion;
    unsigned short* eattr_bf = zregion;
    unsigned short* ebuf = (unsigned short*)alloc((size_t)EE * 128 * 2);
    float* s_src   = (float*)alloc((size_t)NN * 8 * 4);
    float* s_dst   = (float*)alloc((size_t)NN * 8 * 4);
    float* s_edge  = (float*)alloc((size_t)EE * 8 * 4);
    float* part_e  = (float*)alloc((size_t)2500 * 256 * 4);
    float* part_n  = (float*)alloc((size_t)157 * 256 * 4);
    float* scale_e = (float*)alloc(512);
    float* shift_e = (float*)alloc(512);
    float* scale_n = (float*)alloc(512);
    float* shift_n = (float*)alloc(512);
    float* nupd    = (float*)alloc((size_t)NN * 128 * 4);
    float* ush     = (float*)alloc((size_t)NN * 128 * 4);
    float* Sbuf    = (float*)alloc((size_t)NN * 512 * 4);
    int*   cnt     = (int*)alloc((size_t)NN * 4);
    int*   offs    = (int*)alloc((size_t)(NN + 1) * 4);
    int*   cursor  = (int*)alloc((size_t)NN * 4);
    int*   elist   = (int*)alloc((size_t)EE * 4);
    unsigned short* node_bf = (unsigned short*)alloc((size_t)NN * 128 * 2);
    unsigned short* Wt      = (unsigned short*)alloc((size_t)128 * 384 * 2);
    unsigned short* WtA     = (unsigned short*)alloc((size_t)8 * 128 * 128 * 2);
    unsigned short* WnT     = (unsigned short*)alloc((size_t)128 * 128 * 2);
    unsigned short* WcT     = (unsigned short*)alloc((size_t)512 * 256 * 2);
    unsigned short* cat     = (unsigned short*)alloc((size_t)NN * 256 * 2);

    hipMemsetAsync(cnt, 0, (size_t)NN * 4, stream);
    k_hist<<<(EE + 255) / 256, 256, 0, stream>>>(eidx, cnt, EE);
    k_scan<<<1, 1024, 0, stream>>>(cnt, offs, cursor, NN);
    k_scatter<<<(EE + 255) / 256, 256, 0, stream>>>(eidx, cursor, elist, EE);

    // bf16 conversions
    k_f2bf<<<1280, 256, 0, stream>>>(node, node_bf, (long)NN * 128 / 4);
    k_f2bf<<<2048, 256, 0, stream>>>(eattr, eattr_bf, (long)EE * 128 / 4);
    k_wtg<<<(384 * 128 + 255) / 256, 256, 0, stream>>>(We, Wt, 384, 128);
    k_wtg<<<(128 * 128 + 255) / 256, 256, 0, stream>>>(Wn, WnT, 128, 128);
    k_wt_att<<<(8 * 128 * 128 + 255) / 256, 256, 0, stream>>>(Watt, WtA);
    k_wt_gru<<<(512 * 256 + 255) / 256, 256, 0, stream>>>(Wk, Wr, WcT);

    // edge pipeline (uses eattr_bf which aliases zbf; must precede k_z_mfma)
    k_edge_mlp_mfma<<<EE / 64, 256, 0, stream>>>(node_bf, eattr_bf, eidx, Wt, be, ebuf, part_e);
    k_bn_fin<<<128, 256, 0, stream>>>(part_e, EE / 64, 1.f / (float)EE,
                                      gamma_e, beta_e, scale_e, shift_e);
    k_edge_final<<<EE / 8, 256, 0, stream>>>(ebuf, scale_e, shift_e, aatt, out_edge, s_edge);

    // node/attention pipeline
    k_z_mfma<<<dim3((NN + 63) / 64, 8), 256, 0, stream>>>(node_bf, WtA, batt, zbf, NN);
    k_snodes<<<NN / 4, 256, 0, stream>>>(zbf, aatt, s_src, s_dst, NN);
    k_agg<<<NN, 128, 0, stream>>>(zbf, s_src, s_dst, s_edge, offs, elist, eidx, cat);

    // node MLP + BN
    k_node_mlp_mfma<<<(NN + 63) / 64, 256, 0, stream>>>(node_bf, WnT, bnb, nupd, part_n, NN);
    k_bn_fin<<<128, 256, 0, stream>>>(part_n, (NN + 63) / 64, 1.f / (float)NN,
                                      gamma_n, beta_n, scale_n, shift_n);

    // GRU
    k_gru_pre<<<(NN * 32 + 255) / 256, 256, 0, stream>>>(nupd, scale_n, shift_n, cat, ush);
    k_gru_mm<<<dim3((NN + 63) / 64, 4), 256, 0, stream>>>(cat, WcT, Sbuf, NN);
    k_gru_gates<<<NN / 2, 256, 0, stream>>>(Sbuf, ush, gbias, out_node);
}

// Round 6
// 337.754 us; speedup vs baseline: 3.3205x; 1.0432x over previous
//
#include <hip/hip_runtime.h>
#include <hip/hip_bf16.h>

#define NN 10000
#define EE 160000
#define FF 128
#define UU 128
#define HH 8
#define BN_EPS 1e-3f

typedef __attribute__((ext_vector_type(8))) short bf16x8;
typedef __attribute__((ext_vector_type(8))) unsigned short u16x8;
typedef __attribute__((ext_vector_type(4))) float f32x4;

static __device__ __forceinline__ unsigned short f2bf(float f) {
    unsigned u = __float_as_uint(f);
    u += 0x7fffu + ((u >> 16) & 1u);
    return (unsigned short)(u >> 16);
}
static __device__ __forceinline__ float bf2f(unsigned short b) {
    return __uint_as_float((unsigned)b << 16);
}

// ---------------- f32 -> bf16 bulk convert (count divisible by 4) ----------------
__global__ void k_f2bf(const float* __restrict__ in, unsigned short* __restrict__ out, long n4) {
    long i = (long)blockIdx.x * 256 + threadIdx.x;
    long stride = (long)gridDim.x * 256;
    for (; i < n4; i += stride) {
        float4 v = reinterpret_cast<const float4*>(in)[i];
        ushort4 o;
        o.x = f2bf(v.x); o.y = f2bf(v.y); o.z = f2bf(v.z); o.w = f2bf(v.w);
        reinterpret_cast<ushort4*>(out)[i] = o;
    }
}

// ---------------- generic W [K][U] f32 -> W^T [U][K] bf16 ----------------
__global__ void k_wtg(const float* __restrict__ W, unsigned short* __restrict__ Wt, int K, int U) {
    int i = blockIdx.x * 256 + threadIdx.x;
    if (i < K * U) {
        int k = i / U, u = i - k * U;
        Wt[u * K + k] = f2bf(W[i]);
    }
}

// ---------------- W_att [8][128][128] f32 -> per-head W^T [8][128][128] bf16 ----------------
__global__ void k_wt_att(const float* __restrict__ W, unsigned short* __restrict__ Wt) {
    int i = blockIdx.x * 256 + threadIdx.x;   // over 8*128*128
    if (i < 8 * 128 * 128) {
        int h = i >> 14, rem = i & 16383, f = rem >> 7, u = rem & 127;
        Wt[h * 16384 + u * 128 + f] = f2bf(W[i]);
    }
}

// ---------------- GRU combined weight: WcT [512][256] bf16 ----------------
__global__ void k_wt_gru(const float* __restrict__ Wk, const float* __restrict__ Wr,
                         unsigned short* __restrict__ WcT) {
    int i = blockIdx.x * 256 + threadIdx.x;   // over 512*256
    if (i >= 512 * 256) return;
    int c = i >> 8, k = i & 255;
    float v;
    if (c < 256)       v = (k < 128) ? Wk[k * 384 + c] : Wr[(k - 128) * 384 + c];
    else if (c < 384)  v = (k < 128) ? Wk[k * 384 + c] : 0.f;
    else               v = (k < 128) ? 0.f : Wr[(k - 128) * 384 + (c - 128)];
    WcT[c * 256 + k] = f2bf(v);
}

// ---------------- CSR construction ----------------
__global__ void k_hist(const int* __restrict__ eidx, int* __restrict__ cnt, int E) {
    int e = blockIdx.x * 256 + threadIdx.x;
    if (e < E) atomicAdd(&cnt[eidx[2 * e]], 1);   // dst = eidx[e][0]
}

__global__ void k_scan(const int* __restrict__ cnt, int* __restrict__ off,
                       int* __restrict__ cursor, int N) {
    __shared__ int s[1024];
    int t = threadIdx.x;
    int run = 0;
    if (t == 0) off[0] = 0;
    for (int base = 0; base < N; base += 1024) {
        int x = (base + t < N) ? cnt[base + t] : 0;
        s[t] = x;
        __syncthreads();
        for (int o = 1; o < 1024; o <<= 1) {
            int v = (t >= o) ? s[t - o] : 0;
            __syncthreads();
            s[t] += v;
            __syncthreads();
        }
        if (base + t < N) {
            off[base + t + 1] = run + s[t];
            cursor[base + t] = run + s[t] - x;
        }
        run += s[1023];
        __syncthreads();
    }
}

__global__ void k_scatter(const int* __restrict__ eidx, int* __restrict__ cursor,
                          int* __restrict__ elist, int E) {
    int e = blockIdx.x * 256 + threadIdx.x;
    if (e < E) {
        int d = eidx[2 * e];
        int p = atomicAdd(&cursor[d], 1);
        elist[p] = e;
    }
}

// ---------------- z (bf16) = node @ W_att[h] + b_att[h], MFMA, LDS-coalesced store ----------------
__global__ void __launch_bounds__(256) k_z_mfma(
        const unsigned short* __restrict__ node_bf, const unsigned short* __restrict__ WtA,
        const float* __restrict__ batt, unsigned short* __restrict__ zbf, int N) {
    __shared__ unsigned short ash[64][136];     // 128 + 8 pad
    int n0 = blockIdx.x * 64;
    int h = blockIdx.y;
    int t = threadIdx.x;
    for (int q = t; q < 64 * 16; q += 256) {
        int r = q >> 4, c = q & 15;
        int n = n0 + r; if (n >= N) n = N - 1;
        *reinterpret_cast<uint4*>(&ash[r][c * 8]) =
            *reinterpret_cast<const uint4*>(node_bf + (size_t)n * 128 + c * 8);
    }
    __syncthreads();

    int wid = t >> 6, lane = t & 63;
    int wm = wid >> 1, wn = wid & 1;
    int lr = lane & 15, lg = lane >> 4;

    f32x4 acc[2][4];
#pragma unroll
    for (int m = 0; m < 2; ++m)
#pragma unroll
        for (int n = 0; n < 4; ++n) acc[m][n] = (f32x4){0.f, 0.f, 0.f, 0.f};

    const unsigned short* Wh = WtA + (size_t)h * 16384;
#pragma unroll
    for (int ks = 0; ks < 4; ++ks) {
        int kb = ks * 32 + lg * 8;
        bf16x8 a0 = *reinterpret_cast<const bf16x8*>(&ash[wm * 32 + lr][kb]);
        bf16x8 a1 = *reinterpret_cast<const bf16x8*>(&ash[wm * 32 + 16 + lr][kb]);
        bf16x8 b[4];
#pragma unroll
        for (int n = 0; n < 4; ++n)
            b[n] = *reinterpret_cast<const bf16x8*>(Wh + (size_t)(wn * 64 + n * 16 + lr) * 128 + kb);
#pragma unroll
        for (int n = 0; n < 4; ++n) {
            acc[0][n] = __builtin_amdgcn_mfma_f32_16x16x32_bf16(a0, b[n], acc[0][n], 0, 0, 0);
            acc[1][n] = __builtin_amdgcn_mfma_f32_16x16x32_bf16(a1, b[n], acc[1][n], 0, 0, 0);
        }
    }

    __syncthreads();                      // A-tile reads done; reuse ash as C-tile
    unsigned short* ot = &ash[0][0];      // [64][136]
#pragma unroll
    for (int n = 0; n < 4; ++n) {
        int col = wn * 64 + n * 16 + lr;
        float bias = batt[h * 128 + col];
#pragma unroll
        for (int m = 0; m < 2; ++m) {
            int rowb = wm * 32 + m * 16 + lg * 4;
#pragma unroll
            for (int r = 0; r < 4; ++r)
                ot[(rowb + r) * 136 + col] = f2bf(acc[m][n][r] + bias);
        }
    }
    __syncthreads();
    for (int q = t; q < 64 * 16; q += 256) {
        int r = q >> 4, c = q & 15;
        int row = n0 + r;
        if (row < N)
            *reinterpret_cast<uint4*>(&zbf[(size_t)row * 1024 + h * 128 + c * 8]) =
                *reinterpret_cast<const uint4*>(&ot[r * 136 + c * 8]);
    }
}

// ---------------- s_src[n,h], s_dst[n,h]: wave=node, lane=(head, 16-col slice) ----------------
__global__ void __launch_bounds__(256) k_snodes(
        const unsigned short* __restrict__ zbf, const float* __restrict__ aatt,
        float* __restrict__ s_src, float* __restrict__ s_dst, int N) {
    int t = threadIdx.x;
    int w = t >> 6, lane = t & 63;
    int n = blockIdx.x * 4 + w;
    if (n >= N) return;
    int h = lane >> 3, p = lane & 7;
    const unsigned short* zp = zbf + (size_t)n * 1024 + h * 128 + p * 16;
    const float* as = aatt + h * 384 + p * 16;
    u16x8 z0 = *reinterpret_cast<const u16x8*>(zp);
    u16x8 z1 = *reinterpret_cast<const u16x8*>(zp + 8);
    float vs = 0.f, vd = 0.f;
#pragma unroll
    for (int j = 0; j < 8; ++j) {
        float zv = bf2f(z0[j]);
        vs = fmaf(zv, as[j], vs);
        vd = fmaf(zv, as[128 + j], vd);
    }
#pragma unroll
    for (int j = 0; j < 8; ++j) {
        float zv = bf2f(z1[j]);
        vs = fmaf(zv, as[8 + j], vs);
        vd = fmaf(zv, as[136 + j], vd);
    }
#pragma unroll
    for (int o = 1; o < 8; o <<= 1) {
        vs += __shfl_xor(vs, o, 64);
        vd += __shfl_xor(vd, o, 64);
    }
    if (p == 0) {
        s_src[n * 8 + h] = vs;
        s_dst[n * 8 + h] = vd;
    }
}

// ---------------- edge MLP via MFMA bf16 + LDS-coalesced store + BN partials ----------------
__global__ void __launch_bounds__(256) k_edge_mlp_mfma(
        const unsigned short* __restrict__ node_bf, const unsigned short* __restrict__ eattr_bf,
        const int* __restrict__ eidx, const unsigned short* __restrict__ Wt,
        const float* __restrict__ be, unsigned short* __restrict__ ebuf, float* __restrict__ part) {
    __shared__ unsigned short ash[64][392];     // 384 + 8 pad
    __shared__ int sd[128];
    __shared__ float sbuf[4][64], qbuf[4][64];
    int e0 = blockIdx.x * 64;
    int t = threadIdx.x;
    if (t < 128) sd[t] = eidx[e0 * 2 + t];      // [e][0]=dst, [e][1]=src
    __syncthreads();
    for (int q = t; q < 64 * 48; q += 256) {
        int r = q / 48, c = q - r * 48;
        const unsigned short* sp;
        if (c < 16)      sp = node_bf + (size_t)sd[r * 2 + 1] * 128 + c * 8;
        else if (c < 32) sp = node_bf + (size_t)sd[r * 2] * 128 + (c - 16) * 8;
        else             sp = eattr_bf + (size_t)(e0 + r) * 128 + (c - 32) * 8;
        *reinterpret_cast<uint4*>(&ash[r][c * 8]) = *reinterpret_cast<const uint4*>(sp);
    }
    __syncthreads();

    int wid = t >> 6, lane = t & 63;
    int wm = wid >> 1, wn = wid & 1;
    int lr = lane & 15, lg = lane >> 4;

    f32x4 acc[2][4];
#pragma unroll
    for (int m = 0; m < 2; ++m)
#pragma unroll
        for (int n = 0; n < 4; ++n) acc[m][n] = (f32x4){0.f, 0.f, 0.f, 0.f};

#pragma unroll
    for (int ks = 0; ks < 12; ++ks) {
        int kb = ks * 32 + lg * 8;
        bf16x8 a0 = *reinterpret_cast<const bf16x8*>(&ash[wm * 32 + lr][kb]);
        bf16x8 a1 = *reinterpret_cast<const bf16x8*>(&ash[wm * 32 + 16 + lr][kb]);
        bf16x8 b[4];
#pragma unroll
        for (int n = 0; n < 4; ++n)
            b[n] = *reinterpret_cast<const bf16x8*>(Wt + (size_t)(wn * 64 + n * 16 + lr) * 384 + kb);
#pragma unroll
        for (int n = 0; n < 4; ++n) {
            acc[0][n] = __builtin_amdgcn_mfma_f32_16x16x32_bf16(a0, b[n], acc[0][n], 0, 0, 0);
            acc[1][n] = __builtin_amdgcn_mfma_f32_16x16x32_bf16(a1, b[n], acc[1][n], 0, 0, 0);
        }
    }

    __syncthreads();                      // A-tile reads done; reuse ash as C-tile [64][136]
    unsigned short* ot = &ash[0][0];
    float s[4] = {0.f, 0.f, 0.f, 0.f}, q[4] = {0.f, 0.f, 0.f, 0.f};
#pragma unroll
    for (int n = 0; n < 4; ++n) {
        int col = wn * 64 + n * 16 + lr;
        float bias = be[col];
#pragma unroll
        for (int m = 0; m < 2; ++m) {
            int rowb = wm * 32 + m * 16 + lg * 4;
#pragma unroll
            for (int r = 0; r < 4; ++r) {
                float v = acc[m][n][r] + bias;
                v = v > 0.f ? v : 0.f;
                ot[(rowb + r) * 136 + col] = f2bf(v);
                s[n] += v;
                q[n] += v * v;
            }
        }
    }
#pragma unroll
    for (int n = 0; n < 4; ++n) {
        s[n] += __shfl_xor(s[n], 16, 64);
        s[n] += __shfl_xor(s[n], 32, 64);
        q[n] += __shfl_xor(q[n], 16, 64);
        q[n] += __shfl_xor(q[n], 32, 64);
    }
    if (lane < 16) {
#pragma unroll
        for (int n = 0; n < 4; ++n) {
            sbuf[wid][n * 16 + lane] = s[n];
            qbuf[wid][n * 16 + lane] = q[n];
        }
    }
    __syncthreads();
    for (int q2 = t; q2 < 64 * 16; q2 += 256) {
        int r = q2 >> 4, c = q2 & 15;
        *reinterpret_cast<uint4*>(&ebuf[(size_t)(e0 + r) * 128 + c * 8]) =
            *reinterpret_cast<const uint4*>(&ot[r * 136 + c * 8]);
    }
    if (t < 128) {
        int half = t >> 6, c = t & 63;
        part[(size_t)blockIdx.x * 256 + t] = sbuf[half][c] + sbuf[2 + half][c];
        part[(size_t)blockIdx.x * 256 + 128 + t] = qbuf[half][c] + qbuf[2 + half][c];
    }
}

// ---------------- node MLP via MFMA: relu(node @ W_node + b) -> bf16, BN partials ----------------
__global__ void __launch_bounds__(256) k_node_mlp_mfma(
        const unsigned short* __restrict__ node_bf, const unsigned short* __restrict__ WnT,
        const float* __restrict__ bn, unsigned short* __restrict__ nupd_bf,
        float* __restrict__ part, int N) {
    __shared__ unsigned short ash[64][136];
    __shared__ float sbuf[4][64], qbuf[4][64];
    int n0 = blockIdx.x * 64;
    int t = threadIdx.x;
    for (int q = t; q < 64 * 16; q += 256) {
        int r = q >> 4, c = q & 15;
        int n = n0 + r; if (n >= N) n = N - 1;
        *reinterpret_cast<uint4*>(&ash[r][c * 8]) =
            *reinterpret_cast<const uint4*>(node_bf + (size_t)n * 128 + c * 8);
    }
    __syncthreads();

    int wid = t >> 6, lane = t & 63;
    int wm = wid >> 1, wn = wid & 1;
    int lr = lane & 15, lg = lane >> 4;

    f32x4 acc[2][4];
#pragma unroll
    for (int m = 0; m < 2; ++m)
#pragma unroll
        for (int n = 0; n < 4; ++n) acc[m][n] = (f32x4){0.f, 0.f, 0.f, 0.f};

#pragma unroll
    for (int ks = 0; ks < 4; ++ks) {
        int kb = ks * 32 + lg * 8;
        bf16x8 a0 = *reinterpret_cast<const bf16x8*>(&ash[wm * 32 + lr][kb]);
        bf16x8 a1 = *reinterpret_cast<const bf16x8*>(&ash[wm * 32 + 16 + lr][kb]);
        bf16x8 b[4];
#pragma unroll
        for (int n = 0; n < 4; ++n)
            b[n] = *reinterpret_cast<const bf16x8*>(WnT + (size_t)(wn * 64 + n * 16 + lr) * 128 + kb);
#pragma unroll
        for (int n = 0; n < 4; ++n) {
            acc[0][n] = __builtin_amdgcn_mfma_f32_16x16x32_bf16(a0, b[n], acc[0][n], 0, 0, 0);
            acc[1][n] = __builtin_amdgcn_mfma_f32_16x16x32_bf16(a1, b[n], acc[1][n], 0, 0, 0);
        }
    }

    __syncthreads();
    unsigned short* ot = &ash[0][0];
    float s[4] = {0.f, 0.f, 0.f, 0.f}, q[4] = {0.f, 0.f, 0.f, 0.f};
#pragma unroll
    for (int n = 0; n < 4; ++n) {
        int col = wn * 64 + n * 16 + lr;
        float bias = bn[col];
#pragma unroll
        for (int m = 0; m < 2; ++m) {
            int rowb = wm * 32 + m * 16 + lg * 4;
#pragma unroll
            for (int r = 0; r < 4; ++r) {
                int row = n0 + rowb + r;
                float v = acc[m][n][r] + bias;
                v = v > 0.f ? v : 0.f;
                ot[(rowb + r) * 136 + col] = f2bf(v);
                if (row < N) { s[n] += v; q[n] += v * v; }
            }
        }
    }
#pragma unroll
    for (int n = 0; n < 4; ++n) {
        s[n] += __shfl_xor(s[n], 16, 64);
        s[n] += __shfl_xor(s[n], 32, 64);
        q[n] += __shfl_xor(q[n], 16, 64);
        q[n] += __shfl_xor(q[n], 32, 64);
    }
    if (lane < 16) {
#pragma unroll
        for (int n = 0; n < 4; ++n) {
            sbuf[wid][n * 16 + lane] = s[n];
            qbuf[wid][n * 16 + lane] = q[n];
        }
    }
    __syncthreads();
    for (int q2 = t; q2 < 64 * 16; q2 += 256) {
        int r = q2 >> 4, c = q2 & 15;
        int row = n0 + r;
        if (row < N)
            *reinterpret_cast<uint4*>(&nupd_bf[(size_t)row * 128 + c * 8]) =
                *reinterpret_cast<const uint4*>(&ot[r * 136 + c * 8]);
    }
    if (t < 128) {
        int half = t >> 6, c = t & 63;
        part[(size_t)blockIdx.x * 256 + t] = sbuf[half][c] + sbuf[2 + half][c];
        part[(size_t)blockIdx.x * 256 + 128 + t] = qbuf[half][c] + qbuf[2 + half][c];
    }
}

// ---------------- BN finalize: scale/shift per column ----------------
__global__ void k_bn_fin(const float* __restrict__ part, int nblk, float invcnt,
                         const float* __restrict__ g, const float* __restrict__ b,
                         float* __restrict__ scale, float* __restrict__ shift) {
    int u = blockIdx.x;               // 128 blocks
    int t = threadIdx.x;              // 256
    float s = 0.f, q = 0.f;
    for (int i = t; i < nblk; i += 256) {
        s += part[(size_t)i * 256 + u];
        q += part[(size_t)i * 256 + 128 + u];
    }
    __shared__ float ls[4], lq[4];
    for (int o = 32; o > 0; o >>= 1) {
        s += __shfl_down(s, o, 64);
        q += __shfl_down(q, o, 64);
    }
    int lane = t & 63, w = t >> 6;
    if (lane == 0) { ls[w] = s; lq[w] = q; }
    __syncthreads();
    if (t == 0) {
        float S = ls[0] + ls[1] + ls[2] + ls[3];
        float Q = lq[0] + lq[1] + lq[2] + lq[3];
        float mean = S * invcnt;
        float var = Q * invcnt - mean * mean;
        float inv = rsqrtf(var + BN_EPS);
        float sc = g[u] * inv;
        scale[u] = sc;
        shift[u] = b[u] - mean * sc;
    }
}

// ---------------- edge finalize: wave=2 edges, lane=4 cols; BN apply + s_edge ----------------
__global__ void __launch_bounds__(256) k_edge_final(
        const unsigned short* __restrict__ ebuf, const float* __restrict__ scale,
        const float* __restrict__ shift, const float* __restrict__ aatt,
        float* __restrict__ eout, float* __restrict__ s_edge) {
    int t = threadIdx.x;
    int w = t >> 6, lane = t & 63;
    int q = lane & 31, half = lane >> 5;
    int e = blockIdx.x * 8 + w * 2 + half;

    float4 sc = *reinterpret_cast<const float4*>(scale + q * 4);
    float4 sh = *reinterpret_cast<const float4*>(shift + q * 4);
    float4 a4[8];
#pragma unroll
    for (int h = 0; h < 8; ++h)
        a4[h] = *reinterpret_cast<const float4*>(aatt + h * 384 + 256 + q * 4);

    ushort4 xb = *reinterpret_cast<const ushort4*>(ebuf + (size_t)e * 128 + q * 4);
    float4 x;
    x.x = bf2f(xb.x) * sc.x + sh.x;
    x.y = bf2f(xb.y) * sc.y + sh.y;
    x.z = bf2f(xb.z) * sc.z + sh.z;
    x.w = bf2f(xb.w) * sc.w + sh.w;
    *reinterpret_cast<float4*>(eout + (size_t)e * 128 + q * 4) = x;

    float v[8];
#pragma unroll
    for (int h = 0; h < 8; ++h)
        v[h] = x.x * a4[h].x + x.y * a4[h].y + x.z * a4[h].z + x.w * a4[h].w;
#pragma unroll
    for (int o = 1; o < 32; o <<= 1) {
#pragma unroll
        for (int h = 0; h < 8; ++h) v[h] += __shfl_xor(v[h], o, 64);
    }
    if (q == 0) {
#pragma unroll
        for (int h = 0; h < 8; ++h) s_edge[e * 8 + h] = v[h];
    }
}

// ---------------- attention softmax + aggregation; writes bf16 into cat[:,0:128] ----------------
__global__ void k_agg(const unsigned short* __restrict__ zbf, const float* __restrict__ s_src,
                      const float* __restrict__ s_dst, const float* __restrict__ s_edge,
                      const int* __restrict__ off, const int* __restrict__ elist,
                      const int* __restrict__ eidx, unsigned short* __restrict__ cat) {
    int n = blockIdx.x;
    int t = threadIdx.x;              // 128
    int beg = off[n], end = off[n + 1];
    int deg = end - beg;
    if (deg == 0) { cat[(size_t)n * 256 + t] = 0; return; }

    float sdh[8];
#pragma unroll
    for (int h = 0; h < 8; ++h) sdh[h] = s_dst[n * 8 + h];

    __shared__ float lred[16];
    __shared__ float wbuf[128][8];
    __shared__ int snbuf[128];

    float mx[8], den[8];
#pragma unroll
    for (int h = 0; h < 8; ++h) { mx[h] = -1e30f; den[h] = 0.f; }

    int lane = t & 63, w = t >> 6;

    // pass 1: running max / denominator (online across chunks of 128)
    for (int c0 = 0; c0 < deg; c0 += 128) {
        int cn = min(128, deg - c0);
        bool act = t < cn;
        int e = 0, sn = 0;
        if (act) { e = elist[beg + c0 + t]; sn = eidx[2 * e + 1]; }
        float lg[8];
#pragma unroll
        for (int h = 0; h < 8; ++h) {
            float x = act ? (s_src[sn * 8 + h] + sdh[h] + s_edge[e * 8 + h]) : -1e30f;
            lg[h] = x >= 0.f ? x : 0.2f * x;
        }
        float cm[8];
#pragma unroll
        for (int h = 0; h < 8; ++h) cm[h] = lg[h];
        for (int o = 32; o > 0; o >>= 1) {
#pragma unroll
            for (int h = 0; h < 8; ++h) cm[h] = fmaxf(cm[h], __shfl_down(cm[h], o, 64));
        }
        if (lane == 0) {
#pragma unroll
            for (int h = 0; h < 8; ++h) lred[w * 8 + h] = cm[h];
        }
        __syncthreads();
#pragma unroll
        for (int h = 0; h < 8; ++h) cm[h] = fmaxf(lred[h], lred[8 + h]);
        __syncthreads();
        float cs[8];
#pragma unroll
        for (int h = 0; h < 8; ++h) cs[h] = act ? __expf(lg[h] - cm[h]) : 0.f;
        for (int o = 32; o > 0; o >>= 1) {
#pragma unroll
            for (int h = 0; h < 8; ++h) cs[h] += __shfl_down(cs[h], o, 64);
        }
        if (lane == 0) {
#pragma unroll
            for (int h = 0; h < 8; ++h) lred[w * 8 + h] = cs[h];
        }
        __syncthreads();
#pragma unroll
        for (int h = 0; h < 8; ++h) {
            float csum = lred[h] + lred[8 + h];
            float nm = fmaxf(mx[h], cm[h]);
            den[h] = den[h] * __expf(mx[h] - nm) + csum * __expf(cm[h] - nm);
            mx[h] = nm;
        }
        __syncthreads();
    }
    float inv[8];
#pragma unroll
    for (int h = 0; h < 8; ++h) inv[h] = 1.f / den[h];

    // pass 2: weights into LDS, then accumulate sum over heads of alpha*z[src]
    float acc = 0.f;
    for (int c0 = 0; c0 < deg; c0 += 128) {
        int cn = min(128, deg - c0);
        if (t < cn) {
            int e = elist[beg + c0 + t];
            int sn = eidx[2 * e + 1];
            snbuf[t] = sn;
#pragma unroll
            for (int h = 0; h < 8; ++h) {
                float x = s_src[sn * 8 + h] + sdh[h] + s_edge[e * 8 + h];
                x = x >= 0.f ? x : 0.2f * x;
                wbuf[t][h] = __expf(x - mx[h]) * inv[h];
            }
        }
        __syncthreads();
        for (int i = 0; i < cn; ++i) {
            int sn = snbuf[i];
            const unsigned short* zr = zbf + (size_t)sn * 1024 + t;
#pragma unroll
            for (int h = 0; h < 8; ++h)
                acc = fmaf(wbuf[i][h], bf2f(zr[h * 128]), acc);
        }
        __syncthreads();
    }
    cat[(size_t)n * 256 + t] = f2bf(fmaxf(acc * 0.125f, 0.f));
}

// ---------------- GRU pre: ush = BN(nupd_bf); cat[:,128:256] = bf16(ush) ----------------
__global__ void k_gru_pre(const unsigned short* __restrict__ nupd_bf, const float* __restrict__ scale,
                          const float* __restrict__ shift, unsigned short* __restrict__ cat,
                          float* __restrict__ ush) {
    int i = blockIdx.x * 256 + threadIdx.x;   // over NN*32
    if (i >= NN * 32) return;
    int n = i >> 5, j4 = (i & 31) * 4;
    ushort4 ub_in = *reinterpret_cast<const ushort4*>(nupd_bf + (size_t)n * 128 + j4);
    float4 sc = *reinterpret_cast<const float4*>(scale + j4);
    float4 sh = *reinterpret_cast<const float4*>(shift + j4);
    float4 uv;
    uv.x = bf2f(ub_in.x) * sc.x + sh.x;
    uv.y = bf2f(ub_in.y) * sc.y + sh.y;
    uv.z = bf2f(ub_in.z) * sc.z + sh.z;
    uv.w = bf2f(ub_in.w) * sc.w + sh.w;
    ushort4 ub;
    ub.x = f2bf(uv.x); ub.y = f2bf(uv.y); ub.z = f2bf(uv.z); ub.w = f2bf(uv.w);
    *reinterpret_cast<ushort4*>(cat + (size_t)n * 256 + 128 + j4) = ub;
    *reinterpret_cast<float4*>(ush + (size_t)n * 128 + j4) = uv;
}

// ---------------- GRU GEMM: S = cat @ Wc  (M x 256 x 512), MFMA, LDS-coalesced store ----------------
__global__ void __launch_bounds__(256) k_gru_mm(
        const unsigned short* __restrict__ cat, const unsigned short* __restrict__ WcT,
        float* __restrict__ S, int N) {
    __shared__ unsigned short ash[64][264];     // 256 + 8 pad (33792 B)
    int n0 = blockIdx.x * 64;
    int g = blockIdx.y;                          // col group 0..3
    int t = threadIdx.x;
    for (int q = t; q < 64 * 32; q += 256) {
        int r = q >> 5, c = q & 31;
        int n = n0 + r; if (n >= N) n = N - 1;
        *reinterpret_cast<uint4*>(&ash[r][c * 8]) =
            *reinterpret_cast<const uint4*>(cat + (size_t)n * 256 + c * 8);
    }
    __syncthreads();

    int wid = t >> 6, lane = t & 63;
    int wm = wid >> 1, wn = wid & 1;
    int lr = lane & 15, lg = lane >> 4;

    f32x4 acc[2][4];
#pragma unroll
    for (int m = 0; m < 2; ++m)
#pragma unroll
        for (int n = 0; n < 4; ++n) acc[m][n] = (f32x4){0.f, 0.f, 0.f, 0.f};

    const unsigned short* Wg = WcT + (size_t)g * 128 * 256;
#pragma unroll
    for (int ks = 0; ks < 8; ++ks) {
        int kb = ks * 32 + lg * 8;
        bf16x8 a0 = *reinterpret_cast<const bf16x8*>(&ash[wm * 32 + lr][kb]);
        bf16x8 a1 = *reinterpret_cast<const bf16x8*>(&ash[wm * 32 + 16 + lr][kb]);
        bf16x8 b[4];
#pragma unroll
        for (int n = 0; n < 4; ++n)
            b[n] = *reinterpret_cast<const bf16x8*>(Wg + (size_t)(wn * 64 + n * 16 + lr) * 256 + kb);
#pragma unroll
        for (int n = 0; n < 4; ++n) {
            acc[0][n] = __builtin_amdgcn_mfma_f32_16x16x32_bf16(a0, b[n], acc[0][n], 0, 0, 0);
            acc[1][n] = __builtin_amdgcn_mfma_f32_16x16x32_bf16(a1, b[n], acc[1][n], 0, 0, 0);
        }
    }

    __syncthreads();
    float* otf = reinterpret_cast<float*>(&ash[0][0]);   // [64][132] f32 (33792 B)
#pragma unroll
    for (int n = 0; n < 4; ++n) {
        int col = wn * 64 + n * 16 + lr;
#pragma unroll
        for (int m = 0; m < 2; ++m) {
            int rowb = wm * 32 + m * 16 + lg * 4;
#pragma unroll
            for (int r = 0; r < 4; ++r)
                otf[(rowb + r) * 132 + col] = acc[m][n][r];
        }
    }
    __syncthreads();
    for (int q = t; q < 64 * 32; q += 256) {
        int r = q >> 5, c = q & 31;
        int row = n0 + r;
        if (row < N)
            *reinterpret_cast<float4*>(&S[(size_t)row * 512 + g * 128 + c * 4]) =
                *reinterpret_cast<const float4*>(&otf[r * 132 + c * 4]);
    }
}

// ---------------- GRU gates: sigmoid/tanh + combine ----------------
__global__ void __launch_bounds__(256) k_gru_gates(
        const float* __restrict__ S, const float* __restrict__ ush,
        const float* __restrict__ gbias, float* __restrict__ outp) {
    int t = threadIdx.x;
    int n = blockIdx.x * 2 + (t >> 7);
    int u = t & 127;
    const float* b0 = gbias;
    const float* b1 = gbias + 384;
    float s0 = S[(size_t)n * 512 + u];
    float s1 = S[(size_t)n * 512 + 128 + u];
    float xh = S[(size_t)n * 512 + 256 + u];
    float rh = S[(size_t)n * 512 + 384 + u];
    float zg = 1.f / (1.f + __expf(-(s0 + b0[u] + b1[u])));
    float rg = 1.f / (1.f + __expf(-(s1 + b0[128 + u] + b1[128 + u])));
    float hh = tanhf(xh + b0[256 + u] + rg * (rh + b1[256 + u]));
    float uv = ush[(size_t)n * 128 + u];
    outp[(size_t)n * 128 + u] = zg * uv + (1.f - zg) * hh;
}

// ---------------- launch ----------------
extern "C" void kernel_launch(void* const* d_in, const int* in_sizes, int n_in,
                              void* d_out, int out_size, void* d_ws, size_t ws_size,
                              hipStream_t stream) {
    const float* node    = (const float*)d_in[0];
    const float* eattr   = (const float*)d_in[1];
    const int*   eidx    = (const int*)d_in[2];
    const float* We      = (const float*)d_in[3];
    const float* be      = (const float*)d_in[4];
    const float* gamma_e = (const float*)d_in[5];
    const float* beta_e  = (const float*)d_in[6];
    const float* Wn      = (const float*)d_in[7];
    const float* bnb     = (const float*)d_in[8];
    const float* gamma_n = (const float*)d_in[9];
    const float* beta_n  = (const float*)d_in[10];
    const float* Watt    = (const float*)d_in[11];
    const float* batt    = (const float*)d_in[12];
    const float* aatt    = (const float*)d_in[13];
    const float* Wk      = (const float*)d_in[14];
    const float* Wr      = (const float*)d_in[15];
    const float* gbias   = (const float*)d_in[16];

    float* out_node = (float*)d_out;
    float* out_edge = out_node + (size_t)NN * UU;

    char* wp = (char*)d_ws;
    auto alloc = [&](size_t bytes) {
        void* p = (void*)wp;
        wp += (bytes + 255) / 256 * 256;
        return p;
    };
    // zbf (bf16, 20.5MB) shares a region with eattr_bf (bf16, 41MB); eattr_bf dead before k_z_mfma
    unsigned short* zregion = (unsigned short*)alloc((size_t)EE * 128 * 2);
    unsigned short* zbf      = zregion;
    unsigned short* eattr_bf = zregion;
    unsigned short* ebuf = (unsigned short*)alloc((size_t)EE * 128 * 2);
    float* s_src   = (float*)alloc((size_t)NN * 8 * 4);
    float* s_dst   = (float*)alloc((size_t)NN * 8 * 4);
    float* s_edge  = (float*)alloc((size_t)EE * 8 * 4);
    float* part_e  = (float*)alloc((size_t)2500 * 256 * 4);
    float* part_n  = (float*)alloc((size_t)157 * 256 * 4);
    float* scale_e = (float*)alloc(512);
    float* shift_e = (float*)alloc(512);
    float* scale_n = (float*)alloc(512);
    float* shift_n = (float*)alloc(512);
    unsigned short* nupd_bf = (unsigned short*)alloc((size_t)NN * 128 * 2);
    float* ush     = (float*)alloc((size_t)NN * 128 * 4);
    float* Sbuf    = (float*)alloc((size_t)NN * 512 * 4);
    int*   cnt     = (int*)alloc((size_t)NN * 4);
    int*   offs    = (int*)alloc((size_t)(NN + 1) * 4);
    int*   cursor  = (int*)alloc((size_t)NN * 4);
    int*   elist   = (int*)alloc((size_t)EE * 4);
    unsigned short* node_bf = (unsigned short*)alloc((size_t)NN * 128 * 2);
    unsigned short* Wt      = (unsigned short*)alloc((size_t)128 * 384 * 2);
    unsigned short* WtA     = (unsigned short*)alloc((size_t)8 * 128 * 128 * 2);
    unsigned short* WnT     = (unsigned short*)alloc((size_t)128 * 128 * 2);
    unsigned short* WcT     = (unsigned short*)alloc((size_t)512 * 256 * 2);
    unsigned short* cat     = (unsigned short*)alloc((size_t)NN * 256 * 2);

    hipMemsetAsync(cnt, 0, (size_t)NN * 4, stream);
    k_hist<<<(EE + 255) / 256, 256, 0, stream>>>(eidx, cnt, EE);
    k_scan<<<1, 1024, 0, stream>>>(cnt, offs, cursor, NN);
    k_scatter<<<(EE + 255) / 256, 256, 0, stream>>>(eidx, cursor, elist, EE);

    // bf16 conversions
    k_f2bf<<<1280, 256, 0, stream>>>(node, node_bf, (long)NN * 128 / 4);
    k_f2bf<<<2048, 256, 0, stream>>>(eattr, eattr_bf, (long)EE * 128 / 4);
    k_wtg<<<(384 * 128 + 255) / 256, 256, 0, stream>>>(We, Wt, 384, 128);
    k_wtg<<<(128 * 128 + 255) / 256, 256, 0, stream>>>(Wn, WnT, 128, 128);
    k_wt_att<<<(8 * 128 * 128 + 255) / 256, 256, 0, stream>>>(Watt, WtA);
    k_wt_gru<<<(512 * 256 + 255) / 256, 256, 0, stream>>>(Wk, Wr, WcT);

    // edge pipeline (uses eattr_bf which aliases zbf; must precede k_z_mfma)
    k_edge_mlp_mfma<<<EE / 64, 256, 0, stream>>>(node_bf, eattr_bf, eidx, Wt, be, ebuf, part_e);
    k_bn_fin<<<128, 256, 0, stream>>>(part_e, EE / 64, 1.f / (float)EE,
                                      gamma_e, beta_e, scale_e, shift_e);
    k_edge_final<<<EE / 8, 256, 0, stream>>>(ebuf, scale_e, shift_e, aatt, out_edge, s_edge);

    // node/attention pipeline
    k_z_mfma<<<dim3((NN + 63) / 64, 8), 256, 0, stream>>>(node_bf, WtA, batt, zbf, NN);
    k_snodes<<<NN / 4, 256, 0, stream>>>(zbf, aatt, s_src, s_dst, NN);
    k_agg<<<NN, 128, 0, stream>>>(zbf, s_src, s_dst, s_edge, offs, elist, eidx, cat);

    // node MLP + BN
    k_node_mlp_mfma<<<(NN + 63) / 64, 256, 0, stream>>>(node_bf, WnT, bnb, nupd_bf, part_n, NN);
    k_bn_fin<<<128, 256, 0, stream>>>(part_n, (NN + 63) / 64, 1.f / (float)NN,
                                      gamma_n, beta_n, scale_n, shift_n);

    // GRU
    k_gru_pre<<<(NN * 32 + 255) / 256, 256, 0, stream>>>(nupd_bf, scale_n, shift_n, cat, ush);
    k_gru_mm<<<dim3((NN + 63) / 64, 4), 256, 0, stream>>>(cat, WcT, Sbuf, NN);
    k_gru_gates<<<NN / 2, 256, 0, stream>>>(Sbuf, ush, gbias, out_node);
}